// Round 7
// baseline (7200.818 us; speedup 1.0000x reference)
//
#include <hip/hip_runtime.h>

typedef unsigned int uint;
typedef unsigned short ushort;
typedef unsigned long long u64;

#define NITEMS 50000
#define NDATA  20000
#define HITCAP 3000000u

// ---------------- ws layout (bytes) ----------------
#define OFF_LSTMOUT   0x0000000ULL  // [64][64][256] f32 = 4 MB   (memset 0: covers t>=len masking)
#define OFF_HX        0x0400000ULL  // u64[2 parity][64 item][256 j] = 256 KB (memset 0: tag 0)
#define OFF_PACKED    0x0440000ULL  // [4096] u64 = 32 KB         (memset 0: argmax identity, bf16 pass)
#define OFF_PACKED2   0x0448000ULL  // [4096] u64 = 32 KB         (memset 0 + prep seeds zero rows)
#define OFF_HITCNT    0x0450000ULL  // uint                        (memset 0)
#define MEMSET_BYTES  0x0451000ULL
#define OFF_QMARGIN   0x0451000ULL  // [4096] f32 (margin, or -1e30 sentinel for zero rows)
#define OFF_XW        0x0560000ULL  // [4096][1024] f32 = 16 MB
#define OFF_QKV       0x1560000ULL  // [4096][768] f32 = 12 MB (cols: 0-255 q, 256-511 k, 512-767 v)
#define OFF_HITBUF    OFF_QKV       // [3M] uint = 12 MB; dead before qkv_kernel writes (rescore<qkv)
#define OFF_WIHT      0x2160000ULL  // [128][1024] f32 transposed W_ih
#define OFF_WQKVT     0x21E0000ULL  // [256][768] f32 transposed Wq|Wk|Wv
#define OFF_BIASIH    0x22A0000ULL  // [1024] f32 (b_ih + b_hh)
#define OFF_BQKV      0x22A1000ULL  // [768] f32
#define OFF_DNSCALE   0x22A2000ULL  // [20000] f32  1/max(norm,eps)
#define OFF_CLOSEST   0x22B6000ULL  // [64][128] f32
#define OFF_AV        0x22BE000ULL  // [128][64] f32 (transposed: [e][b])
#define OFF_DEMB16    0x22C6000ULL  // [20000][128] bf16 = 5.12 MB
#define OFF_A16       0x27A8000ULL  // [4096][128] bf16 = 1 MB  (emb[x], pre-posenc)
// end 0x28A8000 = 42.7 MB

__device__ __forceinline__ ushort f2bf(float f) {
  union { float f; uint u; } v; v.f = f;
  uint u = v.u;
  return (ushort)((u + 0x7FFFu + ((u >> 16) & 1u)) >> 16);  // RNE
}
__device__ __forceinline__ uint fkey(float f) {  // monotone float->uint
  union { float f; uint u; } v; v.f = f;
  return (v.u & 0x80000000u) ? ~v.u : (v.u | 0x80000000u);
}
__device__ __forceinline__ u64 shfl_xor_u64(u64 v, int off) {
  uint lo = (uint)v, hi = (uint)(v >> 32);
  lo = (uint)__shfl_xor((int)lo, off);
  hi = (uint)__shfl_xor((int)hi, off);
  return ((u64)hi << 32) | (u64)lo;
}

typedef __attribute__((ext_vector_type(8))) short short8;   // 8 bf16 (4 VGPRs)
typedef __attribute__((ext_vector_type(4))) float floatx4;  // MFMA acc

#define R32(M) M(0) M(1) M(2) M(3) M(4) M(5) M(6) M(7) M(8) M(9) M(10) M(11) \
  M(12) M(13) M(14) M(15) M(16) M(17) M(18) M(19) M(20) M(21) M(22) M(23) \
  M(24) M(25) M(26) M(27) M(28) M(29) M(30) M(31)

// ================= prep: norms / bf16 conversions / transposes / biases / kNN margins =================
__global__ __launch_bounds__(256) void prep_kernel(
    const int* __restrict__ x,
    const float* __restrict__ emb, const float* __restrict__ demb,
    const float* __restrict__ W_ih,
    const float* __restrict__ Wq, const float* __restrict__ Wk, const float* __restrict__ Wv,
    const float* __restrict__ b_ih, const float* __restrict__ b_hh,
    const float* __restrict__ bq, const float* __restrict__ bk, const float* __restrict__ bv,
    float* __restrict__ dnscale, ushort* __restrict__ demb16, ushort* __restrict__ a16,
    float* __restrict__ wiht, float* __restrict__ wqkvt,
    float* __restrict__ biasih, float* __restrict__ bqkv,
    float* __restrict__ qmargin, u64* __restrict__ packed2)
{
  int blk = blockIdx.x, tid = threadIdx.x;
  if (blk < 5000) {                       // 1/max(||demb_row||, eps)
    int row = blk * 4 + (tid >> 6);
    int lane = tid & 63;
    float2 d = *(const float2*)(demb + (size_t)row * 128 + lane * 2);
    float s = d.x * d.x + d.y * d.y;
    for (int off = 32; off; off >>= 1) s += __shfl_xor(s, off);
    if (lane == 0) dnscale[row] = 1.0f / fmaxf(sqrtf(s), 1e-8f);
  } else if (blk < 6250) {                // demb -> bf16
    size_t base = ((size_t)(blk - 5000) * 256 + tid) * 8;
    float4 f1 = *(const float4*)(demb + base);
    float4 f2 = *(const float4*)(demb + base + 4);
    uint4 o;
    o.x = (uint)f2bf(f1.x) | ((uint)f2bf(f1.y) << 16);
    o.y = (uint)f2bf(f1.z) | ((uint)f2bf(f1.w) << 16);
    o.z = (uint)f2bf(f2.x) | ((uint)f2bf(f2.y) << 16);
    o.w = (uint)f2bf(f2.z) | ((uint)f2bf(f2.w) << 16);
    *(uint4*)(demb16 + base) = o;
  } else if (blk < 6506) {                // emb[x] rows -> bf16 (initial_embs, pre-posenc)
    int idx = (blk - 6250) * 256 + tid;   // < 65536
    int m = idx >> 4, seg = idx & 15;
    const float* src = emb + (size_t)x[m] * 128 + seg * 8;
    float4 f1 = *(const float4*)(src);
    float4 f2 = *(const float4*)(src + 4);
    uint4 o;
    o.x = (uint)f2bf(f1.x) | ((uint)f2bf(f1.y) << 16);
    o.y = (uint)f2bf(f1.z) | ((uint)f2bf(f1.w) << 16);
    o.z = (uint)f2bf(f2.x) | ((uint)f2bf(f2.y) << 16);
    o.w = (uint)f2bf(f2.z) | ((uint)f2bf(f2.w) << 16);
    *(uint4*)(a16 + (size_t)m * 128 + seg * 8) = o;
  } else if (blk < 7018) {                // W_ih (1024,128) -> [e][r]
    int f = (blk - 6506) * 256 + tid;
    int r = f >> 7, e = f & 127;
    wiht[e * 1024 + r] = W_ih[f];
  } else if (blk < 7786) {                // Wq/Wk/Wv (256,256) -> [e][w*256+r]
    int f = (blk - 7018) * 256 + tid;
    int w = f >> 16; int rem = f & 65535;
    int r = rem >> 8, e = rem & 255;
    const float* src = (w == 0) ? Wq : (w == 1) ? Wk : Wv;
    wqkvt[e * 768 + w * 256 + r] = src[rem];
  } else if (blk < 7790) {
    int idx = (blk - 7786) * 256 + tid;
    if (idx < 1024) biasih[idx] = b_ih[idx] + b_hh[idx];
  } else if (blk < 7793) {
    int idx = (blk - 7790) * 256 + tid;
    if (idx < 768) {
      int w = idx >> 8; int r = idx & 255;
      const float* src = (w == 0) ? bq : (w == 1) ? bk : bv;
      bqkv[idx] = src[r];
    }
  } else {                                // kNN margin per query row + zero-row seeds
    int row = (blk - 7793) * 4 + (tid >> 6);   // 1024 blocks -> 4096 rows
    int lane = tid & 63;
    float2 d = *(const float2*)(emb + (size_t)x[row] * 128 + lane * 2);
    float s = d.x * d.x + d.y * d.y;
    for (int off = 32; off; off >>= 1) s += __shfl_xor(s, off);
    if (lane == 0) {
      if (s == 0.f) {
        qmargin[row] = -1e30f;            // sentinel: never record candidates
        // all sims exactly +0 -> argmax = first index (n=0), exact
        packed2[row] = ((u64)fkey(0.0f) << 32) | 0xFFFFFFFFull;
      } else {
        // PROVABLE bound: |sim_bf16 - sim_exact| <= 2*2^-8*||q||(1+d) (q AND d rounding,
        // Cauchy-Schwarz) ~= 0.0157||q||; 0.017||q|| adds fp32-accum slack.
        qmargin[row] = 0.017f * sqrtf(s) + 1e-5f;
      }
    }
  }
}

// ================= xW = (emb[x]+posenc) @ W_ih^T + (b_ih+b_hh) =================
__global__ __launch_bounds__(256) void xw_kernel(
    const int* __restrict__ x, const float* __restrict__ emb,
    const float* __restrict__ wiht, const float* __restrict__ biasih,
    float* __restrict__ xW)
{
  __shared__ __align__(16) float At[128 * 16];   // [e][m]
  int blk = blockIdx.x, tid = threadIdx.x;
  int m0 = blk * 16;
  for (int c = 0; c < 8; ++c) {
    int idx = c * 256 + tid;
    int mm = idx >> 7, e = idx & 127;
    int m = m0 + mm;
    int bcol = m & 63;                 // PositionalEncoding indexed by BATCH (faithful quirk)
    int xv = x[m];
    float val = emb[(size_t)xv * 128 + e];
    int j = e >> 1;
    float arg = (float)bcol * __expf((float)j * -0.14391157f);  // exp(-j*ln(10000)/64)
    val += (e & 1) ? cosf(arg) : sinf(arg);
    At[e * 16 + mm] = val;
  }
  __syncthreads();
  int quad = tid >> 6, l = tid & 63;
  for (int rp = 0; rp < 4; ++rp) {
    int r = rp * 256 + l * 4;
    float acc[4][4] = {};
    for (int e = 0; e < 128; ++e) {
      float4 wv4 = *(const float4*)(wiht + e * 1024 + r);
      float4 av4 = *(const float4*)(At + e * 16 + quad * 4);
      float am[4] = {av4.x, av4.y, av4.z, av4.w};
      float wr4[4] = {wv4.x, wv4.y, wv4.z, wv4.w};
      #pragma unroll
      for (int mi = 0; mi < 4; ++mi)
        #pragma unroll
        for (int ri = 0; ri < 4; ++ri)
          acc[mi][ri] += am[mi] * wr4[ri];
    }
    float4 bv4 = *(const float4*)(biasih + r);
    #pragma unroll
    for (int mi = 0; mi < 4; ++mi) {
      size_t m = (size_t)(m0 + quad * 4 + mi);
      float4 o;
      o.x = acc[mi][0] + bv4.x; o.y = acc[mi][1] + bv4.y;
      o.z = acc[mi][2] + bv4.z; o.w = acc[mi][3] + bv4.w;
      *(float4*)(xW + m * 1024 + r) = o;
    }
  }
}

// ================= kNN single pass: bf16 MFMA GEMM, dbuf LDS staging,
// tile-0 SEED (no recording) then argmax + margin-candidate recording.
// Superset proof: candidate recorded iff sim >= running_best - margin;
// running_best <= final_best, so anything within margin of final best is recorded. =================
__global__ __launch_bounds__(256) void knn_kernel(
    const ushort* __restrict__ a16, const ushort* __restrict__ demb16,
    const float* __restrict__ dnscale, const float* __restrict__ qmargin,
    u64* __restrict__ packed, uint* __restrict__ hitcnt, uint* __restrict__ hitbuf)
{
  __shared__ __align__(16) ushort b_sh[2][64 * 144];
  int blk = blockIdx.x, tid = threadIdx.x;
  int chunk = blk & 7, mt = blk >> 3;      // blk%8=chunk -> chunk pinned per XCD
  int wv = tid >> 6, lane = tid & 63;
  int col = lane & 15, quad = lane >> 4;
  int M0 = mt * 128;
  short8 afrag[2][4];
  float marg[2][4];
  #pragma unroll
  for (int s = 0; s < 2; ++s) {
    int mrow = M0 + s * 64 + wv * 16 + col;
    #pragma unroll
    for (int kf = 0; kf < 4; ++kf)
      afrag[s][kf] = *(const short8*)(a16 + (size_t)mrow * 128 + kf * 32 + quad * 8);
    #pragma unroll
    for (int r = 0; r < 4; ++r)
      marg[s][r] = qmargin[M0 + s * 64 + wv * 16 + quad * 4 + r];
  }
  float best[2][4] = {{-1e30f,-1e30f,-1e30f,-1e30f},{-1e30f,-1e30f,-1e30f,-1e30f}};
  int bidx[2][4] = {};
  int nbase = chunk * 2500, nend = nbase + 2500;
  const int niter = 40;                    // ceil(2500/64)
  int srow = tid >> 4, sseg = tid & 15;
  uint4 stg[4]; float scr[4];
  // prefetch tile 0
  #pragma unroll
  for (int p = 0; p < 4; ++p) {
    int n = nbase + p * 16 + srow;
    uint4 v = {0u,0u,0u,0u};
    if (n < nend) v = *(const uint4*)(demb16 + (size_t)n * 128 + sseg * 8);
    stg[p] = v;
  }
  #pragma unroll
  for (int ns = 0; ns < 4; ++ns) {
    int n = nbase + ns * 16 + col;
    scr[ns] = (n < nend) ? dnscale[n] : 0.f;
  }
  // ---- SEED: tile 0 argmax only, no recording (prevents hitbuf flood) ----
  {
    ushort* bsh = b_sh[0];
    #pragma unroll
    for (int p = 0; p < 4; ++p)
      *(uint4*)(&bsh[(p * 16 + srow) * 144 + sseg * 8]) = stg[p];
    __syncthreads();
    #pragma unroll
    for (int ns = 0; ns < 4; ++ns) {
      short8 bfr[4];
      #pragma unroll
      for (int kf = 0; kf < 4; ++kf)
        bfr[kf] = *(const short8*)(&bsh[(ns * 16 + col) * 144 + kf * 32 + quad * 8]);
      int n = nbase + ns * 16 + col;
      float sc = scr[ns];
      bool valid = (n < nend);
      #pragma unroll
      for (int s = 0; s < 2; ++s) {
        floatx4 acc = {0.f, 0.f, 0.f, 0.f};
        #pragma unroll
        for (int kf = 0; kf < 4; ++kf)
          acc = __builtin_amdgcn_mfma_f32_16x16x32_bf16(afrag[s][kf], bfr[kf], acc, 0, 0, 0);
        #pragma unroll
        for (int r = 0; r < 4; ++r) {
          float sim = acc[r] * sc;
          if (valid && sim > best[s][r]) { best[s][r] = sim; bidx[s][r] = n; }
        }
      }
    }
    __syncthreads();
  }
  // ---- main loop: records candidates >= best - marg (incl. tile 0 again) ----
  for (int it = 0; it < niter; ++it) {
    int n0 = nbase + it * 64;
    ushort* bsh = b_sh[it & 1];
    #pragma unroll
    for (int p = 0; p < 4; ++p)
      *(uint4*)(&bsh[(p * 16 + srow) * 144 + sseg * 8]) = stg[p];
    float mysc[4] = {scr[0], scr[1], scr[2], scr[3]};
    __syncthreads();
    if (it + 1 < niter) {                  // prefetch next tile while computing this one
      int nb = n0 + 64;
      #pragma unroll
      for (int p = 0; p < 4; ++p) {
        int n = nb + p * 16 + srow;
        uint4 v = {0u,0u,0u,0u};
        if (n < nend) v = *(const uint4*)(demb16 + (size_t)n * 128 + sseg * 8);
        stg[p] = v;
      }
      #pragma unroll
      for (int ns = 0; ns < 4; ++ns) {
        int n = nb + ns * 16 + col;
        scr[ns] = (n < nend) ? dnscale[n] : 0.f;
      }
    }
    #pragma unroll
    for (int ns = 0; ns < 4; ++ns) {
      short8 bfr[4];
      #pragma unroll
      for (int kf = 0; kf < 4; ++kf)
        bfr[kf] = *(const short8*)(&bsh[(ns * 16 + col) * 144 + kf * 32 + quad * 8]);
      int n = n0 + ns * 16 + col;
      float sc = mysc[ns];
      bool valid = (n < nend);
      #pragma unroll
      for (int s = 0; s < 2; ++s) {
        floatx4 acc = {0.f, 0.f, 0.f, 0.f};
        #pragma unroll
        for (int kf = 0; kf < 4; ++kf)
          acc = __builtin_amdgcn_mfma_f32_16x16x32_bf16(afrag[s][kf], bfr[kf], acc, 0, 0, 0);
        #pragma unroll
        for (int r = 0; r < 4; ++r) {        // D[row=quad*4+r][col=lane&15]
          float sim = acc[r] * sc;
          bool hit = valid && (sim >= best[s][r] - marg[s][r]);
          if (valid && sim > best[s][r]) { best[s][r] = sim; bidx[s][r] = n; }
          u64 mask = __ballot(hit);
          if (mask) {                        // wave-aggregated append (rare after seed)
            uint lcnt = (uint)__popcll(mask);
            int leader = __ffsll((unsigned long long)mask) - 1;
            uint base = 0;
            if (lane == leader) base = atomicAdd(hitcnt, lcnt);
            base = (uint)__shfl((int)base, leader);
            if (hit) {
              uint off = (uint)__popcll(mask & ((1ull << lane) - 1ull));
              uint pos = base + off;
              if (pos < HITCAP) {
                uint mm = (uint)(M0 + s * 64 + wv * 16 + quad * 4 + r);
                hitbuf[pos] = (mm << 15) | (uint)n;
              }
            }
          }
        }
      }
    }
  }
  #pragma unroll
  for (int s = 0; s < 2; ++s)
    #pragma unroll
    for (int r = 0; r < 4; ++r) {
      u64 p = ((u64)fkey(best[s][r]) << 32) | (u64)(0xFFFFFFFFu - (uint)bidx[s][r]);
      for (int off = 1; off < 16; off <<= 1) {
        u64 o = shfl_xor_u64(p, off);
        if (o > p) p = o;
      }
      if (col == 0) {
        int m = M0 + s * 64 + wv * 16 + quad * 4 + r;
        atomicMax((unsigned long long*)&packed[m], (unsigned long long)p);
      }
    }
}

// ================= rescore: exact-dot EVERY recorded candidate (no filter — no razor edges).
// Threads gid<4096 also rescore the bf16 winner -> packed2[m] is ALWAYS valid. =================
__global__ __launch_bounds__(256) void rescore_kernel(
    const uint* __restrict__ hitbuf, const uint* __restrict__ hitcnt,
    const u64* __restrict__ packed,
    const int* __restrict__ x, const float* __restrict__ emb,
    const float* __restrict__ demb, const float* __restrict__ dnscale,
    u64* __restrict__ packed2)
{
  uint gid = blockIdx.x * 256 + threadIdx.x;   // grid 512 -> 131072 threads
  if (gid < 4096) {                            // guaranteed fallback: bf16 winner exact
    uint m = gid;
    uint n = 0xFFFFFFFFu - (uint)(packed[m] & 0xFFFFFFFFull);
    if (n < NDATA) {
      const float* q = emb + (size_t)x[m] * 128;
      const float* d = demb + (size_t)n * 128;
      double p = 0.0;
      #pragma unroll 8
      for (int e = 0; e < 128; e += 2) {
        float2 qv = *(const float2*)(q + e);
        float2 dv = *(const float2*)(d + e);
        p += (double)qv.x * (double)dv.x + (double)qv.y * (double)dv.y;
      }
      float sx = (float)(p * (double)dnscale[n]);
      u64 key = ((u64)fkey(sx) << 32) | (u64)(0xFFFFFFFFu - n);
      atomicMax((unsigned long long*)&packed2[m], (unsigned long long)key);
    }
  }
  uint cnt = *hitcnt; if (cnt > HITCAP) cnt = HITCAP;
  for (uint h = gid; h < cnt; h += 131072u) {
    uint rec = hitbuf[h];
    uint m = rec >> 15, n = rec & 0x7FFFu;
    if (n >= NDATA) continue;
    const float* q = emb + (size_t)x[m] * 128;
    const float* d = demb + (size_t)n * 128;
    double p = 0.0;
    #pragma unroll 8
    for (int e = 0; e < 128; e += 2) {
      float2 qv = *(const float2*)(q + e);
      float2 dv = *(const float2*)(d + e);
      p += (double)qv.x * (double)dv.x + (double)qv.y * (double)dv.y;
    }
    float sx = (float)(p * (double)dnscale[n]);
    u64 key = ((u64)fkey(sx) << 32) | (u64)(0xFFFFFFFFu - n);
    atomicMax((unsigned long long*)&packed2[m], (unsigned long long)key);
  }
}

// ================= LSTM: 4 blocks/item, asm-pinned reg-resident W_hh, fence-free
// relaxed-atomic h exchange ({f32,u32 tag} packed, parity double-buffer) =================
__global__ __launch_bounds__(512, 2) void lstm_kernel(
    const int* __restrict__ lengths, const float* __restrict__ Whh,
    const float* __restrict__ xW, float* __restrict__ lstm_out,
    u64* __restrict__ hx)
{
  __shared__ __align__(16) float h_sh[256];
  __shared__ float part_sh[512];
  int blk = blockIdx.x, tid = threadIdx.x;
  int b = blk & 63, q = blk >> 6;          // item b blocks {b,64+b,128+b,192+b}
  int row_local = tid >> 1, half = tid & 1;
  int gate = row_local >> 6, jloc = row_local & 63;
  int grow = gate * 256 + q * 64 + jloc;
  const float4* wp4 = (const float4*)(Whh + (size_t)grow * 256 + half * 128);
#define WDECL(i) float4 tt##i = wp4[i]; \
  float w##i##x = tt##i.x, w##i##y = tt##i.y, w##i##z = tt##i.z, w##i##w = tt##i.w;
  R32(WDECL)
  // pin: asm-produced values cannot be rematerialized -> loads can't sink into the loop
#define WPIN(i) asm volatile("" : "+v"(w##i##x), "+v"(w##i##y), "+v"(w##i##z), "+v"(w##i##w));
  R32(WPIN)
  int len = lengths[b];
  if (tid < 256) h_sh[tid] = 0.f;
  float cval = 0.f;
  int jr = (tid < q * 64) ? tid : tid + 64;  // remote-j map for tid<192 (skips own quarter)
  __syncthreads();
  for (int t = 0; t < len; ++t) {
    if (t > 0) {
      if (tid < 192) {                     // fetch partners' h_t (tag t, parity t&1)
        u64* slot = hx + (((size_t)(t & 1) * 64 + b) * 256 + jr);
        u64 v = 0; int guard = 0;
        while (true) {
          v = __hip_atomic_load(slot, __ATOMIC_RELAXED, __HIP_MEMORY_SCOPE_AGENT);
          if ((uint)v == (uint)t || ++guard > (1 << 22)) break;
          __builtin_amdgcn_s_sleep(1);
        }
        union { uint u; float f; } cv; cv.u = (uint)(v >> 32);
        h_sh[jr] = cv.f;
      }
      __syncthreads();
    }
    const float4* h4 = (const float4*)(h_sh + half * 128);
    float acc = 0.f;
#define WACC(i) { float4 hv = h4[i]; \
    acc += w##i##x * hv.x + w##i##y * hv.y + w##i##z * hv.z + w##i##w * hv.w; }
    R32(WACC)
    part_sh[tid] = acc;
    __syncthreads();
    if (tid < 64) {
      const float* xwrow = xW + ((size_t)t * 64 + b) * 1024 + q * 64 + tid;
      float gi = part_sh[tid * 2]         + part_sh[tid * 2 + 1]         + xwrow[0];
      float gf = part_sh[(64 + tid) * 2]  + part_sh[(64 + tid) * 2 + 1]  + xwrow[256];
      float gg = part_sh[(128 + tid) * 2] + part_sh[(128 + tid) * 2 + 1] + xwrow[512];
      float go = part_sh[(192 + tid) * 2] + part_sh[(192 + tid) * 2 + 1] + xwrow[768];
      float ii = 1.f / (1.f + __expf(-gi));
      float ff = 1.f / (1.f + __expf(-gf));
      float oo = 1.f / (1.f + __expf(-go));
      cval = ff * cval + ii * tanhf(gg);
      float hv = oo * tanhf(cval);
      int j = q * 64 + tid;
      lstm_out[((size_t)b * 64 + t) * 256 + j] = hv;
      h_sh[j] = hv;                        // own quarter stays local
      union { float f; uint u; } cu; cu.f = hv;
      u64 pk = ((u64)cu.u << 32) | (u64)(uint)(t + 1);
      __hip_atomic_store(hx + (((size_t)((t + 1) & 1) * 64 + b) * 256 + j), pk,
                         __ATOMIC_RELAXED, __HIP_MEMORY_SCOPE_AGENT);
    }
    __syncthreads();                       // h_sh own-writes ordered before next-iter reads
  }
}

// ================= closest = mean_t data_emb[idx] =================
__global__ __launch_bounds__(128) void closest_kernel(
    const u64* __restrict__ packed2, const float* __restrict__ demb,
    float* __restrict__ closest)
{
  int b = blockIdx.x, tid = threadIdx.x;
  float s = 0.f;
  for (int t = 0; t < 64; ++t) {
    uint low = (uint)(packed2[t * 64 + b] & 0xFFFFFFFFull);
    uint n = 0xFFFFFFFFu - low;
    if (n >= NDATA) n = 0;                 // safety clamp: never page-fault
    s += demb[(size_t)n * 128 + tid];
  }
  closest[b * 128 + tid] = s * (1.0f / 64.0f);
}

// ================= q/k/v = lstm_out @ W{q,k,v}^T + bias =================
__global__ __launch_bounds__(256) void qkv_kernel(
    const float* __restrict__ lstm_out, const float* __restrict__ wqkvt,
    const float* __restrict__ bqkv, float* __restrict__ qkv)
{
  __shared__ __align__(16) float At[256 * 16];   // [e][m]
  int blk = blockIdx.x, tid = threadIdx.x;
  int m0 = blk * 16;
  for (int c = 0; c < 16; ++c)
    At[tid * 16 + c] = lstm_out[((size_t)m0 + c) * 256 + tid];
  __syncthreads();
  int quad = tid >> 6, l = tid & 63;
  for (int rp = 0; rp < 3; ++rp) {
    int r = rp * 256 + l * 4;
    float acc[4][4] = {};
    for (int e = 0; e < 256; ++e) {
      float4 wv4 = *(const float4*)(wqkvt + (size_t)e * 768 + r);
      float4 av4 = *(const float4*)(At + e * 16 + quad * 4);
      float am[4] = {av4.x, av4.y, av4.z, av4.w};
      float wr4[4] = {wv4.x, wv4.y, wv4.z, wv4.w};
      #pragma unroll
      for (int mi = 0; mi < 4; ++mi)
        #pragma unroll
        for (int ri = 0; ri < 4; ++ri)
          acc[mi][ri] += am[mi] * wr4[ri];
    }
    float4 bv4 = *(const float4*)(bqkv + r);
    #pragma unroll
    for (int mi = 0; mi < 4; ++mi) {
      size_t m = (size_t)(m0 + quad * 4 + mi);
      float4 o;
      o.x = acc[mi][0] + bv4.x; o.y = acc[mi][1] + bv4.y;
      o.z = acc[mi][2] + bv4.z; o.w = acc[mi][3] + bv4.w;
      *(float4*)(qkv + m * 768 + r) = o;
    }
  }
}

// ================= attention: softmax col-sums, weighted V, W_out proj, *closest =================
__global__ __launch_bounds__(256) void attn_kernel(
    const float* __restrict__ qkv, const int* __restrict__ lengths,
    const float* __restrict__ closest, const float* __restrict__ W_out,
    const float* __restrict__ b_out, float* __restrict__ av)
{
  __shared__ float k_sh[64 * 257];               // stride 257 -> conflict-free row reads
  __shared__ __align__(16) float q_sh[4 * 256];
  __shared__ float wpart[4 * 64];
  __shared__ float wtot[64];
  __shared__ float out_sh[256];
  int b = blockIdx.x, tid = threadIdx.x;
  int wv = tid >> 6, lane = tid & 63;
  int len = lengths[b];
  for (int s = 0; s < 64; ++s)
    k_sh[s * 257 + tid] = qkv[((size_t)b * 64 + s) * 768 + 256 + tid];
  wpart[tid] = 0.f;
  for (int tq = 0; tq < 16; ++tq) {
    __syncthreads();
    #pragma unroll
    for (int c = 0; c < 4; ++c)
      q_sh[c * 256 + tid] = qkv[((size_t)b * 64 + tq * 4 + c) * 768 + tid];
    __syncthreads();
    const float* krow = k_sh + lane * 257;
    const float* qrow = q_sh + wv * 256;
    float sc = 0.f;
    #pragma unroll 8
    for (int h = 0; h < 256; ++h)
      sc += qrow[h] * krow[h];
    sc *= 0.0625f;                         // 1/sqrt(256)
    bool vs = (lane < len);                // key-position mask
    float scm = vs ? sc : -1e30f;
    float mx = scm;
    for (int off = 32; off; off >>= 1) mx = fmaxf(mx, __shfl_xor(mx, off));
    float e = vs ? __expf(sc - mx) : 0.f;
    float sum = e;
    for (int off = 32; off; off >>= 1) sum += __shfl_xor(sum, off);
    wpart[wv * 64 + lane] += e / sum;
  }
  __syncthreads();
  if (tid < 64)
    wtot[tid] = (wpart[tid] + wpart[64 + tid] + wpart[128 + tid] + wpart[192 + tid]) * (1.0f / 64.0f);
  __syncthreads();
  {
    float acc = 0.f;
    for (int s = 0; s < 64; ++s)
      acc += wtot[s] * qkv[((size_t)b * 64 + s) * 768 + 512 + tid];
    out_sh[tid] = acc;
  }
  __syncthreads();
  if (tid < 128) {
    const float4* wr = (const float4*)(W_out + (size_t)tid * 256);
    float p = b_out[tid];
    #pragma unroll
    for (int c = 0; c < 64; ++c) {
      float4 u = wr[c];
      p += out_sh[c * 4 + 0] * u.x + out_sh[c * 4 + 1] * u.y
         + out_sh[c * 4 + 2] * u.z + out_sh[c * 4 + 3] * u.w;
    }
    av[tid * 64 + b] = p * closest[b * 128 + tid];   // [e][b] for wave-uniform loads later
  }
}

// ================= out[b][i] = av[:,b] . emb_table[i] =================
__global__ __launch_bounds__(256) void final_kernel(
    const float* __restrict__ emb, const float* __restrict__ av,
    float* __restrict__ out)
{
  int i = blockIdx.x * 256 + threadIdx.x;
  if (i >= NITEMS) return;
  const float4* row = (const float4*)(emb + (size_t)i * 128);
  float acc[64];
  #pragma unroll
  for (int bb = 0; bb < 64; ++bb) acc[bb] = 0.f;
  for (int e4 = 0; e4 < 32; ++e4) {
    float4 u = row[e4];
    float wvv[4] = {u.x, u.y, u.z, u.w};
    const float* ab = av + e4 * 4 * 64;    // wave-uniform addresses -> scalar pipe
    #pragma unroll
    for (int j = 0; j < 4; ++j) {
      #pragma unroll
      for (int bb = 0; bb < 64; ++bb)
        acc[bb] += wvv[j] * ab[j * 64 + bb];
    }
  }
  #pragma unroll
  for (int bb = 0; bb < 64; ++bb)
    out[(size_t)bb * NITEMS + i] = acc[bb];
}

// ================= launch =================
extern "C" void kernel_launch(void* const* d_in, const int* in_sizes, int n_in,
                              void* d_out, int out_size, void* d_ws, size_t ws_size,
                              hipStream_t stream)
{
  const int*   x       = (const int*)d_in[0];
  const int*   lengths = (const int*)d_in[1];
  const float* emb     = (const float*)d_in[2];
  const float* demb    = (const float*)d_in[3];
  const float* W_ih    = (const float*)d_in[4];
  const float* W_hh    = (const float*)d_in[5];
  const float* b_ih    = (const float*)d_in[6];
  const float* b_hh    = (const float*)d_in[7];
  const float* Wq      = (const float*)d_in[8];
  const float* bq      = (const float*)d_in[9];
  const float* Wk      = (const float*)d_in[10];
  const float* bk      = (const float*)d_in[11];
  const float* Wv      = (const float*)d_in[12];
  const float* bv      = (const float*)d_in[13];
  const float* W_out   = (const float*)d_in[14];
  const float* b_out   = (const float*)d_in[15];

  char* ws = (char*)d_ws;
  float*  lstm_out = (float*)(ws + OFF_LSTMOUT);
  u64*    hx       = (u64*)(ws + OFF_HX);
  u64*    packed   = (u64*)(ws + OFF_PACKED);
  u64*    packed2  = (u64*)(ws + OFF_PACKED2);
  uint*   hitcnt   = (uint*)(ws + OFF_HITCNT);
  float*  qmargin  = (float*)(ws + OFF_QMARGIN);
  uint*   hitbuf   = (uint*)(ws + OFF_HITBUF);
  float*  xW       = (float*)(ws + OFF_XW);
  float*  qkv      = (float*)(ws + OFF_QKV);
  float*  wiht     = (float*)(ws + OFF_WIHT);
  float*  wqkvt    = (float*)(ws + OFF_WQKVT);
  float*  biasih   = (float*)(ws + OFF_BIASIH);
  float*  bqkv     = (float*)(ws + OFF_BQKV);
  float*  dnscale  = (float*)(ws + OFF_DNSCALE);
  float*  closest  = (float*)(ws + OFF_CLOSEST);
  float*  av       = (float*)(ws + OFF_AV);
  ushort* demb16   = (ushort*)(ws + OFF_DEMB16);
  ushort* a16      = (ushort*)(ws + OFF_A16);

  hipMemsetAsync(d_ws, 0, (size_t)MEMSET_BYTES, stream);

  hipLaunchKernelGGL(prep_kernel, dim3(8817), dim3(256), 0, stream,
                     x, emb, demb, W_ih, Wq, Wk, Wv, b_ih, b_hh, bq, bk, bv,
                     dnscale, demb16, a16, wiht, wqkvt, biasih, bqkv,
                     qmargin, packed2);
  hipLaunchKernelGGL(xw_kernel, dim3(256), dim3(256), 0, stream,
                     x, emb, wiht, biasih, xW);
  hipLaunchKernelGGL(knn_kernel, dim3(256), dim3(256), 0, stream,
                     a16, demb16, dnscale, qmargin, packed, hitcnt, hitbuf);
  hipLaunchKernelGGL(rescore_kernel, dim3(512), dim3(256), 0, stream,
                     hitbuf, hitcnt, packed, x, emb, demb, dnscale, packed2);
  hipLaunchKernelGGL(lstm_kernel, dim3(256), dim3(512), 0, stream,
                     lengths, W_hh, xW, lstm_out, hx);
  hipLaunchKernelGGL(closest_kernel, dim3(64), dim3(128), 0, stream,
                     packed2, demb, closest);
  hipLaunchKernelGGL(qkv_kernel, dim3(256), dim3(256), 0, stream,
                     lstm_out, wqkvt, bqkv, qkv);
  hipLaunchKernelGGL(attn_kernel, dim3(64), dim3(256), 0, stream,
                     qkv, lengths, closest, W_out, b_out, av);
  hipLaunchKernelGGL(final_kernel, dim3(196), dim3(256), 0, stream,
                     emb, av, (float*)d_out);
}

// Round 8
// 1012.809 us; speedup vs baseline: 7.1097x; 7.1097x over previous
//
#include <hip/hip_runtime.h>

typedef unsigned int uint;
typedef unsigned short ushort;
typedef unsigned long long u64;

#define NITEMS 50000
#define NDATA  20000
#define HITCAP 3000000u

// ---------------- ws layout (bytes) ----------------
#define OFF_LSTMOUT   0x0000000ULL  // [64][64][256] f32 = 4 MB   (memset 0: covers t>=len masking)
#define OFF_HX        0x0400000ULL  // u64[2 parity][64 item][256 j] = 256 KB (memset 0: tag 0)
#define OFF_PACKED    0x0440000ULL  // [4096] u64 = 32 KB         (memset 0: argmax identity, bf16 pass)
#define OFF_PACKED2   0x0448000ULL  // [4096] u64 = 32 KB         (memset 0 + prep seeds zero rows)
#define OFF_HITCNT    0x0450000ULL  // uint                        (memset 0)
#define MEMSET_BYTES  0x0451000ULL
#define OFF_QMARGIN   0x0451000ULL  // [4096] f32 (margin, or -1e30 sentinel for zero rows)
#define OFF_XW        0x0560000ULL  // [4096][1024] f32 = 16 MB
#define OFF_QKV       0x1560000ULL  // [4096][768] f32 = 12 MB (cols: 0-255 q, 256-511 k, 512-767 v)
#define OFF_HITBUF    OFF_QKV       // [3M] uint = 12 MB; dead before qkv_kernel writes (rescore<qkv)
#define OFF_WIHT      0x2160000ULL  // [128][1024] f32 transposed W_ih
#define OFF_WQKVT     0x21E0000ULL  // [256][768] f32 transposed Wq|Wk|Wv
#define OFF_BIASIH    0x22A0000ULL  // [1024] f32 (b_ih + b_hh)
#define OFF_BQKV      0x22A1000ULL  // [768] f32
#define OFF_DNSCALE   0x22A2000ULL  // [20000] f32  1/max(norm,eps)
#define OFF_CLOSEST   0x22B6000ULL  // [64][128] f32
#define OFF_AV        0x22BE000ULL  // [128][64] f32 (transposed: [e][b])
#define OFF_DEMB16    0x22C6000ULL  // [20000][128] bf16 = 5.12 MB
#define OFF_A16       0x27A8000ULL  // [4096][128] bf16 = 1 MB  (emb[x], pre-posenc)
// end 0x28A8000 = 42.7 MB

__device__ __forceinline__ ushort f2bf(float f) {
  union { float f; uint u; } v; v.f = f;
  uint u = v.u;
  return (ushort)((u + 0x7FFFu + ((u >> 16) & 1u)) >> 16);  // RNE
}
__device__ __forceinline__ uint fkey(float f) {  // monotone float->uint
  union { float f; uint u; } v; v.f = f;
  return (v.u & 0x80000000u) ? ~v.u : (v.u | 0x80000000u);
}
__device__ __forceinline__ u64 shfl_xor_u64(u64 v, int off) {
  uint lo = (uint)v, hi = (uint)(v >> 32);
  lo = (uint)__shfl_xor((int)lo, off);
  hi = (uint)__shfl_xor((int)hi, off);
  return ((u64)hi << 32) | (u64)lo;
}

typedef __attribute__((ext_vector_type(8))) short short8;   // 8 bf16 (4 VGPRs)
typedef __attribute__((ext_vector_type(4))) float floatx4;  // MFMA acc

#define R32(M) M(0) M(1) M(2) M(3) M(4) M(5) M(6) M(7) M(8) M(9) M(10) M(11) \
  M(12) M(13) M(14) M(15) M(16) M(17) M(18) M(19) M(20) M(21) M(22) M(23) \
  M(24) M(25) M(26) M(27) M(28) M(29) M(30) M(31)

// ================= prep: norms / bf16 conversions / transposes / biases / kNN margins =================
__global__ __launch_bounds__(256) void prep_kernel(
    const int* __restrict__ x,
    const float* __restrict__ emb, const float* __restrict__ demb,
    const float* __restrict__ W_ih,
    const float* __restrict__ Wq, const float* __restrict__ Wk, const float* __restrict__ Wv,
    const float* __restrict__ b_ih, const float* __restrict__ b_hh,
    const float* __restrict__ bq, const float* __restrict__ bk, const float* __restrict__ bv,
    float* __restrict__ dnscale, ushort* __restrict__ demb16, ushort* __restrict__ a16,
    float* __restrict__ wiht, float* __restrict__ wqkvt,
    float* __restrict__ biasih, float* __restrict__ bqkv,
    float* __restrict__ qmargin, u64* __restrict__ packed2)
{
  int blk = blockIdx.x, tid = threadIdx.x;
  if (blk < 5000) {                       // 1/max(||demb_row||, eps)
    int row = blk * 4 + (tid >> 6);
    int lane = tid & 63;
    float2 d = *(const float2*)(demb + (size_t)row * 128 + lane * 2);
    float s = d.x * d.x + d.y * d.y;
    for (int off = 32; off; off >>= 1) s += __shfl_xor(s, off);
    if (lane == 0) dnscale[row] = 1.0f / fmaxf(sqrtf(s), 1e-8f);
  } else if (blk < 6250) {                // demb -> bf16
    size_t base = ((size_t)(blk - 5000) * 256 + tid) * 8;
    float4 f1 = *(const float4*)(demb + base);
    float4 f2 = *(const float4*)(demb + base + 4);
    uint4 o;
    o.x = (uint)f2bf(f1.x) | ((uint)f2bf(f1.y) << 16);
    o.y = (uint)f2bf(f1.z) | ((uint)f2bf(f1.w) << 16);
    o.z = (uint)f2bf(f2.x) | ((uint)f2bf(f2.y) << 16);
    o.w = (uint)f2bf(f2.z) | ((uint)f2bf(f2.w) << 16);
    *(uint4*)(demb16 + base) = o;
  } else if (blk < 6506) {                // emb[x] rows -> bf16 (initial_embs, pre-posenc)
    int idx = (blk - 6250) * 256 + tid;   // < 65536
    int m = idx >> 4, seg = idx & 15;
    const float* src = emb + (size_t)x[m] * 128 + seg * 8;
    float4 f1 = *(const float4*)(src);
    float4 f2 = *(const float4*)(src + 4);
    uint4 o;
    o.x = (uint)f2bf(f1.x) | ((uint)f2bf(f1.y) << 16);
    o.y = (uint)f2bf(f1.z) | ((uint)f2bf(f1.w) << 16);
    o.z = (uint)f2bf(f2.x) | ((uint)f2bf(f2.y) << 16);
    o.w = (uint)f2bf(f2.z) | ((uint)f2bf(f2.w) << 16);
    *(uint4*)(a16 + (size_t)m * 128 + seg * 8) = o;
  } else if (blk < 7018) {                // W_ih (1024,128) -> [e][r]
    int f = (blk - 6506) * 256 + tid;
    int r = f >> 7, e = f & 127;
    wiht[e * 1024 + r] = W_ih[f];
  } else if (blk < 7786) {                // Wq/Wk/Wv (256,256) -> [e][w*256+r]
    int f = (blk - 7018) * 256 + tid;
    int w = f >> 16; int rem = f & 65535;
    int r = rem >> 8, e = rem & 255;
    const float* src = (w == 0) ? Wq : (w == 1) ? Wk : Wv;
    wqkvt[e * 768 + w * 256 + r] = src[rem];
  } else if (blk < 7790) {
    int idx = (blk - 7786) * 256 + tid;
    if (idx < 1024) biasih[idx] = b_ih[idx] + b_hh[idx];
  } else if (blk < 7793) {
    int idx = (blk - 7790) * 256 + tid;
    if (idx < 768) {
      int w = idx >> 8; int r = idx & 255;
      const float* src = (w == 0) ? bq : (w == 1) ? bk : bv;
      bqkv[idx] = src[r];
    }
  } else {                                // kNN margin per query row + zero-row seeds
    int row = (blk - 7793) * 4 + (tid >> 6);   // 1024 blocks -> 4096 rows
    int lane = tid & 63;
    float2 d = *(const float2*)(emb + (size_t)x[row] * 128 + lane * 2);
    float s = d.x * d.x + d.y * d.y;
    for (int off = 32; off; off >>= 1) s += __shfl_xor(s, off);
    if (lane == 0) {
      if (s == 0.f) {
        qmargin[row] = -1e30f;            // sentinel: thr = best+1e30 -> no hits ever
        // all sims exactly +0 -> argmax = first index (n=0), exact
        packed2[row] = ((u64)fkey(0.0f) << 32) | 0xFFFFFFFFull;
      } else {
        // PROVABLE bound: |sim_bf16 - sim_exact| <= 2*2^-8*||q|| (q AND d rounding,
        // Cauchy-Schwarz) ~= 0.0157||q||; 0.017||q|| adds fp32-accum slack.
        qmargin[row] = 0.017f * sqrtf(s) + 1e-5f;
      }
    }
  }
}

// ================= xW = (emb[x]+posenc) @ W_ih^T + (b_ih+b_hh) =================
__global__ __launch_bounds__(256) void xw_kernel(
    const int* __restrict__ x, const float* __restrict__ emb,
    const float* __restrict__ wiht, const float* __restrict__ biasih,
    float* __restrict__ xW)
{
  __shared__ __align__(16) float At[128 * 16];   // [e][m]
  int blk = blockIdx.x, tid = threadIdx.x;
  int m0 = blk * 16;
  for (int c = 0; c < 8; ++c) {
    int idx = c * 256 + tid;
    int mm = idx >> 7, e = idx & 127;
    int m = m0 + mm;
    int bcol = m & 63;                 // PositionalEncoding indexed by BATCH (faithful quirk)
    int xv = x[m];
    float val = emb[(size_t)xv * 128 + e];
    int j = e >> 1;
    float arg = (float)bcol * __expf((float)j * -0.14391157f);  // exp(-j*ln(10000)/64)
    val += (e & 1) ? cosf(arg) : sinf(arg);
    At[e * 16 + mm] = val;
  }
  __syncthreads();
  int quad = tid >> 6, l = tid & 63;
  for (int rp = 0; rp < 4; ++rp) {
    int r = rp * 256 + l * 4;
    float acc[4][4] = {};
    for (int e = 0; e < 128; ++e) {
      float4 wv4 = *(const float4*)(wiht + e * 1024 + r);
      float4 av4 = *(const float4*)(At + e * 16 + quad * 4);
      float am[4] = {av4.x, av4.y, av4.z, av4.w};
      float wr4[4] = {wv4.x, wv4.y, wv4.z, wv4.w};
      #pragma unroll
      for (int mi = 0; mi < 4; ++mi)
        #pragma unroll
        for (int ri = 0; ri < 4; ++ri)
          acc[mi][ri] += am[mi] * wr4[ri];
    }
    float4 bv4 = *(const float4*)(biasih + r);
    #pragma unroll
    for (int mi = 0; mi < 4; ++mi) {
      size_t m = (size_t)(m0 + quad * 4 + mi);
      float4 o;
      o.x = acc[mi][0] + bv4.x; o.y = acc[mi][1] + bv4.y;
      o.z = acc[mi][2] + bv4.z; o.w = acc[mi][3] + bv4.w;
      *(float4*)(xW + m * 1024 + r) = o;
    }
  }
}

// ================= kNN: two MFMA sweeps per chunk.
// Sweep A: pure argmax (no atomics). Butterfly-reduce -> chunk-final per-row best.
// Sweep B: restage (L2-hot, chunk pinned per XCD) + record sim >= chunk_best - margin.
// chunk_best <= global_best -> recorded set is a superset of {sim >= global_best - margin},
// which (by the margin bound) contains the true exact argmax. ~40K hits total. =================
__global__ __launch_bounds__(256) void knn_kernel(
    const ushort* __restrict__ a16, const ushort* __restrict__ demb16,
    const float* __restrict__ dnscale, const float* __restrict__ qmargin,
    u64* __restrict__ packed, uint* __restrict__ hitcnt, uint* __restrict__ hitbuf)
{
  __shared__ __align__(16) ushort b_sh[2][64 * 144];
  int blk = blockIdx.x, tid = threadIdx.x;
  int chunk = blk & 7, mt = blk >> 3;      // blk%8=chunk -> chunk pinned per XCD
  int wv = tid >> 6, lane = tid & 63;
  int col = lane & 15, quad = lane >> 4;
  int M0 = mt * 128;
  short8 afrag[2][4];
  #pragma unroll
  for (int s = 0; s < 2; ++s) {
    int mrow = M0 + s * 64 + wv * 16 + col;
    #pragma unroll
    for (int kf = 0; kf < 4; ++kf)
      afrag[s][kf] = *(const short8*)(a16 + (size_t)mrow * 128 + kf * 32 + quad * 8);
  }
  float best[2][4] = {{-1e30f,-1e30f,-1e30f,-1e30f},{-1e30f,-1e30f,-1e30f,-1e30f}};
  int bidx[2][4] = {};
  int nbase = chunk * 2500, nend = nbase + 2500;
  const int niter = 40;                    // ceil(2500/64)
  int srow = tid >> 4, sseg = tid & 15;
  uint4 stg[4]; float scr[4];

  // ================== SWEEP A: pure argmax ==================
  #pragma unroll
  for (int p = 0; p < 4; ++p) {
    int n = nbase + p * 16 + srow;
    uint4 v = {0u,0u,0u,0u};
    if (n < nend) v = *(const uint4*)(demb16 + (size_t)n * 128 + sseg * 8);
    stg[p] = v;
  }
  #pragma unroll
  for (int ns = 0; ns < 4; ++ns) {
    int n = nbase + ns * 16 + col;
    scr[ns] = (n < nend) ? dnscale[n] : 0.f;
  }
  for (int it = 0; it < niter; ++it) {
    int n0 = nbase + it * 64;
    ushort* bsh = b_sh[it & 1];
    #pragma unroll
    for (int p = 0; p < 4; ++p)
      *(uint4*)(&bsh[(p * 16 + srow) * 144 + sseg * 8]) = stg[p];
    float mysc[4] = {scr[0], scr[1], scr[2], scr[3]};
    __syncthreads();
    if (it + 1 < niter) {                  // prefetch next tile while computing this one
      int nb = n0 + 64;
      #pragma unroll
      for (int p = 0; p < 4; ++p) {
        int n = nb + p * 16 + srow;
        uint4 v = {0u,0u,0u,0u};
        if (n < nend) v = *(const uint4*)(demb16 + (size_t)n * 128 + sseg * 8);
        stg[p] = v;
      }
      #pragma unroll
      for (int ns = 0; ns < 4; ++ns) {
        int n = nb + ns * 16 + col;
        scr[ns] = (n < nend) ? dnscale[n] : 0.f;
      }
    }
    #pragma unroll
    for (int ns = 0; ns < 4; ++ns) {
      short8 bfr[4];
      #pragma unroll
      for (int kf = 0; kf < 4; ++kf)
        bfr[kf] = *(const short8*)(&bsh[(ns * 16 + col) * 144 + kf * 32 + quad * 8]);
      int n = n0 + ns * 16 + col;
      float sc = mysc[ns];
      bool valid = (n < nend);
      #pragma unroll
      for (int s = 0; s < 2; ++s) {
        floatx4 acc = {0.f, 0.f, 0.f, 0.f};
        #pragma unroll
        for (int kf = 0; kf < 4; ++kf)
          acc = __builtin_amdgcn_mfma_f32_16x16x32_bf16(afrag[s][kf], bfr[kf], acc, 0, 0, 0);
        #pragma unroll
        for (int r = 0; r < 4; ++r) {        // D[row=quad*4+r][col=lane&15]
          float sim = acc[r] * sc;
          if (valid && sim > best[s][r]) { best[s][r] = sim; bidx[s][r] = n; }
        }
      }
    }
  }
  // chunk-final per-row best (butterfly over the 16 col lanes) + global argmax output
  float thr[2][4];
  #pragma unroll
  for (int s = 0; s < 2; ++s)
    #pragma unroll
    for (int r = 0; r < 4; ++r) {
      u64 p = ((u64)fkey(best[s][r]) << 32) | (u64)(0xFFFFFFFFu - (uint)bidx[s][r]);
      #pragma unroll
      for (int off = 1; off < 16; off <<= 1) {   // col bits only: stays in row group
        u64 o = shfl_xor_u64(p, off);
        if (o > p) p = o;
      }
      int m = M0 + s * 64 + wv * 16 + quad * 4 + r;
      union { uint u; float f; } bu;
      uint k = (uint)(p >> 32);
      bu.u = (k & 0x80000000u) ? (k & 0x7FFFFFFFu) : ~k;   // unfkey
      thr[s][r] = bu.f - qmargin[m];
      if (col == 0)
        atomicMax((unsigned long long*)&packed[m], (unsigned long long)p);
    }
  __syncthreads();

  // ================== SWEEP B: record candidates >= thr ==================
  #pragma unroll
  for (int p = 0; p < 4; ++p) {
    int n = nbase + p * 16 + srow;
    uint4 v = {0u,0u,0u,0u};
    if (n < nend) v = *(const uint4*)(demb16 + (size_t)n * 128 + sseg * 8);
    stg[p] = v;
  }
  #pragma unroll
  for (int ns = 0; ns < 4; ++ns) {
    int n = nbase + ns * 16 + col;
    scr[ns] = (n < nend) ? dnscale[n] : 0.f;
  }
  for (int it = 0; it < niter; ++it) {
    int n0 = nbase + it * 64;
    ushort* bsh = b_sh[it & 1];
    #pragma unroll
    for (int p = 0; p < 4; ++p)
      *(uint4*)(&bsh[(p * 16 + srow) * 144 + sseg * 8]) = stg[p];
    float mysc[4] = {scr[0], scr[1], scr[2], scr[3]};
    __syncthreads();
    if (it + 1 < niter) {
      int nb = n0 + 64;
      #pragma unroll
      for (int p = 0; p < 4; ++p) {
        int n = nb + p * 16 + srow;
        uint4 v = {0u,0u,0u,0u};
        if (n < nend) v = *(const uint4*)(demb16 + (size_t)n * 128 + sseg * 8);
        stg[p] = v;
      }
      #pragma unroll
      for (int ns = 0; ns < 4; ++ns) {
        int n = nb + ns * 16 + col;
        scr[ns] = (n < nend) ? dnscale[n] : 0.f;
      }
    }
    #pragma unroll
    for (int ns = 0; ns < 4; ++ns) {
      short8 bfr[4];
      #pragma unroll
      for (int kf = 0; kf < 4; ++kf)
        bfr[kf] = *(const short8*)(&bsh[(ns * 16 + col) * 144 + kf * 32 + quad * 8]);
      int n = n0 + ns * 16 + col;
      float sc = mysc[ns];
      bool valid = (n < nend);
      #pragma unroll
      for (int s = 0; s < 2; ++s) {
        floatx4 acc = {0.f, 0.f, 0.f, 0.f};
        #pragma unroll
        for (int kf = 0; kf < 4; ++kf)
          acc = __builtin_amdgcn_mfma_f32_16x16x32_bf16(afrag[s][kf], bfr[kf], acc, 0, 0, 0);
        #pragma unroll
        for (int r = 0; r < 4; ++r) {
          float sim = acc[r] * sc;
          bool hit = valid && (sim >= thr[s][r]);   // ~5e-4 probability
          u64 mask = __ballot(hit);
          if (mask) {                               // ~99% of ballots skip this
            uint lcnt = (uint)__popcll(mask);
            int leader = __ffsll((unsigned long long)mask) - 1;
            uint base = 0;
            if (lane == leader) base = atomicAdd(hitcnt, lcnt);
            base = (uint)__shfl((int)base, leader);
            if (hit) {
              uint off = (uint)__popcll(mask & ((1ull << lane) - 1ull));
              uint pos = base + off;
              if (pos < HITCAP) {
                uint mm = (uint)(M0 + s * 64 + wv * 16 + quad * 4 + r);
                hitbuf[pos] = (mm << 15) | (uint)n;
              }
            }
          }
        }
      }
    }
  }
}

// ================= rescore: exact-dot EVERY recorded candidate (no filter — no razor edges).
// Threads gid<4096 also rescore the bf16 winner -> packed2[m] is ALWAYS valid. =================
__global__ __launch_bounds__(256) void rescore_kernel(
    const uint* __restrict__ hitbuf, const uint* __restrict__ hitcnt,
    const u64* __restrict__ packed,
    const int* __restrict__ x, const float* __restrict__ emb,
    const float* __restrict__ demb, const float* __restrict__ dnscale,
    u64* __restrict__ packed2)
{
  uint gid = blockIdx.x * 256 + threadIdx.x;   // grid 512 -> 131072 threads
  if (gid < 4096) {                            // guaranteed fallback: bf16 winner exact
    uint m = gid;
    uint n = 0xFFFFFFFFu - (uint)(packed[m] & 0xFFFFFFFFull);
    if (n < NDATA) {
      const float* q = emb + (size_t)x[m] * 128;
      const float* d = demb + (size_t)n * 128;
      double p = 0.0;
      #pragma unroll 8
      for (int e = 0; e < 128; e += 2) {
        float2 qv = *(const float2*)(q + e);
        float2 dv = *(const float2*)(d + e);
        p += (double)qv.x * (double)dv.x + (double)qv.y * (double)dv.y;
      }
      float sx = (float)(p * (double)dnscale[n]);
      u64 key = ((u64)fkey(sx) << 32) | (u64)(0xFFFFFFFFu - n);
      atomicMax((unsigned long long*)&packed2[m], (unsigned long long)key);
    }
  }
  uint cnt = *hitcnt; if (cnt > HITCAP) cnt = HITCAP;
  for (uint h = gid; h < cnt; h += 131072u) {
    uint rec = hitbuf[h];
    uint m = rec >> 15, n = rec & 0x7FFFu;
    if (n >= NDATA) continue;
    const float* q = emb + (size_t)x[m] * 128;
    const float* d = demb + (size_t)n * 128;
    double p = 0.0;
    #pragma unroll 8
    for (int e = 0; e < 128; e += 2) {
      float2 qv = *(const float2*)(q + e);
      float2 dv = *(const float2*)(d + e);
      p += (double)qv.x * (double)dv.x + (double)qv.y * (double)dv.y;
    }
    float sx = (float)(p * (double)dnscale[n]);
    u64 key = ((u64)fkey(sx) << 32) | (u64)(0xFFFFFFFFu - n);
    atomicMax((unsigned long long*)&packed2[m], (unsigned long long)key);
  }
}

// ================= LSTM: 4 blocks/item, asm-pinned reg-resident W_hh, fence-free
// relaxed-atomic h exchange ({f32,u32 tag} packed, parity double-buffer) =================
__global__ __launch_bounds__(512, 2) void lstm_kernel(
    const int* __restrict__ lengths, const float* __restrict__ Whh,
    const float* __restrict__ xW, float* __restrict__ lstm_out,
    u64* __restrict__ hx)
{
  __shared__ __align__(16) float h_sh[256];
  __shared__ float part_sh[512];
  int blk = blockIdx.x, tid = threadIdx.x;
  int b = blk & 63, q = blk >> 6;          // item b blocks {b,64+b,128+b,192+b}
  int row_local = tid >> 1, half = tid & 1;
  int gate = row_local >> 6, jloc = row_local & 63;
  int grow = gate * 256 + q * 64 + jloc;
  const float4* wp4 = (const float4*)(Whh + (size_t)grow * 256 + half * 128);
#define WDECL(i) float4 tt##i = wp4[i]; \
  float w##i##x = tt##i.x, w##i##y = tt##i.y, w##i##z = tt##i.z, w##i##w = tt##i.w;
  R32(WDECL)
  // pin: asm-produced values cannot be rematerialized -> loads can't sink into the loop
#define WPIN(i) asm volatile("" : "+v"(w##i##x), "+v"(w##i##y), "+v"(w##i##z), "+v"(w##i##w));
  R32(WPIN)
  int len = lengths[b];
  if (tid < 256) h_sh[tid] = 0.f;
  float cval = 0.f;
  int jr = (tid < q * 64) ? tid : tid + 64;  // remote-j map for tid<192 (skips own quarter)
  __syncthreads();
  for (int t = 0; t < len; ++t) {
    if (t > 0) {
      if (tid < 192) {                     // fetch partners' h_t (tag t, parity t&1)
        u64* slot = hx + (((size_t)(t & 1) * 64 + b) * 256 + jr);
        u64 v = 0; int guard = 0;
        while (true) {
          v = __hip_atomic_load(slot, __ATOMIC_RELAXED, __HIP_MEMORY_SCOPE_AGENT);
          if ((uint)v == (uint)t || ++guard > (1 << 22)) break;
          __builtin_amdgcn_s_sleep(1);
        }
        union { uint u; float f; } cv; cv.u = (uint)(v >> 32);
        h_sh[jr] = cv.f;
      }
      __syncthreads();
    }
    const float4* h4 = (const float4*)(h_sh + half * 128);
    float acc = 0.f;
#define WACC(i) { float4 hv = h4[i]; \
    acc += w##i##x * hv.x + w##i##y * hv.y + w##i##z * hv.z + w##i##w * hv.w; }
    R32(WACC)
    part_sh[tid] = acc;
    __syncthreads();
    if (tid < 64) {
      const float* xwrow = xW + ((size_t)t * 64 + b) * 1024 + q * 64 + tid;
      float gi = part_sh[tid * 2]         + part_sh[tid * 2 + 1]         + xwrow[0];
      float gf = part_sh[(64 + tid) * 2]  + part_sh[(64 + tid) * 2 + 1]  + xwrow[256];
      float gg = part_sh[(128 + tid) * 2] + part_sh[(128 + tid) * 2 + 1] + xwrow[512];
      float go = part_sh[(192 + tid) * 2] + part_sh[(192 + tid) * 2 + 1] + xwrow[768];
      float ii = 1.f / (1.f + __expf(-gi));
      float ff = 1.f / (1.f + __expf(-gf));
      float oo = 1.f / (1.f + __expf(-go));
      cval = ff * cval + ii * tanhf(gg);
      float hv = oo * tanhf(cval);
      int j = q * 64 + tid;
      lstm_out[((size_t)b * 64 + t) * 256 + j] = hv;
      h_sh[j] = hv;                        // own quarter stays local
      union { float f; uint u; } cu; cu.f = hv;
      u64 pk = ((u64)cu.u << 32) | (u64)(uint)(t + 1);
      __hip_atomic_store(hx + (((size_t)((t + 1) & 1) * 64 + b) * 256 + j), pk,
                         __ATOMIC_RELAXED, __HIP_MEMORY_SCOPE_AGENT);
    }
    __syncthreads();                       // h_sh own-writes ordered before next-iter reads
  }
}

// ================= closest = mean_t data_emb[idx] =================
__global__ __launch_bounds__(128) void closest_kernel(
    const u64* __restrict__ packed2, const float* __restrict__ demb,
    float* __restrict__ closest)
{
  int b = blockIdx.x, tid = threadIdx.x;
  float s = 0.f;
  for (int t = 0; t < 64; ++t) {
    uint low = (uint)(packed2[t * 64 + b] & 0xFFFFFFFFull);
    uint n = 0xFFFFFFFFu - low;
    if (n >= NDATA) n = 0;                 // safety clamp: never page-fault
    s += demb[(size_t)n * 128 + tid];
  }
  closest[b * 128 + tid] = s * (1.0f / 64.0f);
}

// ================= q/k/v = lstm_out @ W{q,k,v}^T + bias =================
__global__ __launch_bounds__(256) void qkv_kernel(
    const float* __restrict__ lstm_out, const float* __restrict__ wqkvt,
    const float* __restrict__ bqkv, float* __restrict__ qkv)
{
  __shared__ __align__(16) float At[256 * 16];   // [e][m]
  int blk = blockIdx.x, tid = threadIdx.x;
  int m0 = blk * 16;
  for (int c = 0; c < 16; ++c)
    At[tid * 16 + c] = lstm_out[((size_t)m0 + c) * 256 + tid];
  __syncthreads();
  int quad = tid >> 6, l = tid & 63;
  for (int rp = 0; rp < 3; ++rp) {
    int r = rp * 256 + l * 4;
    float acc[4][4] = {};
    for (int e = 0; e < 256; ++e) {
      float4 wv4 = *(const float4*)(wqkvt + (size_t)e * 768 + r);
      float4 av4 = *(const float4*)(At + e * 16 + quad * 4);
      float am[4] = {av4.x, av4.y, av4.z, av4.w};
      float wr4[4] = {wv4.x, wv4.y, wv4.z, wv4.w};
      #pragma unroll
      for (int mi = 0; mi < 4; ++mi)
        #pragma unroll
        for (int ri = 0; ri < 4; ++ri)
          acc[mi][ri] += am[mi] * wr4[ri];
    }
    float4 bv4 = *(const float4*)(bqkv + r);
    #pragma unroll
    for (int mi = 0; mi < 4; ++mi) {
      size_t m = (size_t)(m0 + quad * 4 + mi);
      float4 o;
      o.x = acc[mi][0] + bv4.x; o.y = acc[mi][1] + bv4.y;
      o.z = acc[mi][2] + bv4.z; o.w = acc[mi][3] + bv4.w;
      *(float4*)(qkv + m * 768 + r) = o;
    }
  }
}

// ================= attention: softmax col-sums, weighted V, W_out proj, *closest =================
__global__ __launch_bounds__(256) void attn_kernel(
    const float* __restrict__ qkv, const int* __restrict__ lengths,
    const float* __restrict__ closest, const float* __restrict__ W_out,
    const float* __restrict__ b_out, float* __restrict__ av)
{
  __shared__ float k_sh[64 * 257];               // stride 257 -> conflict-free row reads
  __shared__ __align__(16) float q_sh[4 * 256];
  __shared__ float wpart[4 * 64];
  __shared__ float wtot[64];
  __shared__ float out_sh[256];
  int b = blockIdx.x, tid = threadIdx.x;
  int wv = tid >> 6, lane = tid & 63;
  int len = lengths[b];
  for (int s = 0; s < 64; ++s)
    k_sh[s * 257 + tid] = qkv[((size_t)b * 64 + s) * 768 + 256 + tid];
  wpart[tid] = 0.f;
  for (int tq = 0; tq < 16; ++tq) {
    __syncthreads();
    #pragma unroll
    for (int c = 0; c < 4; ++c)
      q_sh[c * 256 + tid] = qkv[((size_t)b * 64 + tq * 4 + c) * 768 + tid];
    __syncthreads();
    const float* krow = k_sh + lane * 257;
    const float* qrow = q_sh + wv * 256;
    float sc = 0.f;
    #pragma unroll 8
    for (int h = 0; h < 256; ++h)
      sc += qrow[h] * krow[h];
    sc *= 0.0625f;                         // 1/sqrt(256)
    bool vs = (lane < len);                // key-position mask
    float scm = vs ? sc : -1e30f;
    float mx = scm;
    for (int off = 32; off; off >>= 1) mx = fmaxf(mx, __shfl_xor(mx, off));
    float e = vs ? __expf(sc - mx) : 0.f;
    float sum = e;
    for (int off = 32; off; off >>= 1) sum += __shfl_xor(sum, off);
    wpart[wv * 64 + lane] += e / sum;
  }
  __syncthreads();
  if (tid < 64)
    wtot[tid] = (wpart[tid] + wpart[64 + tid] + wpart[128 + tid] + wpart[192 + tid]) * (1.0f / 64.0f);
  __syncthreads();
  {
    float acc = 0.f;
    for (int s = 0; s < 64; ++s)
      acc += wtot[s] * qkv[((size_t)b * 64 + s) * 768 + 512 + tid];
    out_sh[tid] = acc;
  }
  __syncthreads();
  if (tid < 128) {
    const float4* wr = (const float4*)(W_out + (size_t)tid * 256);
    float p = b_out[tid];
    #pragma unroll
    for (int c = 0; c < 64; ++c) {
      float4 u = wr[c];
      p += out_sh[c * 4 + 0] * u.x + out_sh[c * 4 + 1] * u.y
         + out_sh[c * 4 + 2] * u.z + out_sh[c * 4 + 3] * u.w;
    }
    av[tid * 64 + b] = p * closest[b * 128 + tid];   // [e][b] for wave-uniform loads later
  }
}

// ================= out[b][i] = av[:,b] . emb_table[i] =================
__global__ __launch_bounds__(256) void final_kernel(
    const float* __restrict__ emb, const float* __restrict__ av,
    float* __restrict__ out)
{
  int i = blockIdx.x * 256 + threadIdx.x;
  if (i >= NITEMS) return;
  const float4* row = (const float4*)(emb + (size_t)i * 128);
  float acc[64];
  #pragma unroll
  for (int bb = 0; bb < 64; ++bb) acc[bb] = 0.f;
  for (int e4 = 0; e4 < 32; ++e4) {
    float4 u = row[e4];
    float wvv[4] = {u.x, u.y, u.z, u.w};
    const float* ab = av + e4 * 4 * 64;    // wave-uniform addresses -> scalar pipe
    #pragma unroll
    for (int j = 0; j < 4; ++j) {
      #pragma unroll
      for (int bb = 0; bb < 64; ++bb)
        acc[bb] += wvv[j] * ab[j * 64 + bb];
    }
  }
  #pragma unroll
  for (int bb = 0; bb < 64; ++bb)
    out[(size_t)bb * NITEMS + i] = acc[bb];
}

// ================= launch =================
extern "C" void kernel_launch(void* const* d_in, const int* in_sizes, int n_in,
                              void* d_out, int out_size, void* d_ws, size_t ws_size,
                              hipStream_t stream)
{
  const int*   x       = (const int*)d_in[0];
  const int*   lengths = (const int*)d_in[1];
  const float* emb     = (const float*)d_in[2];
  const float* demb    = (const float*)d_in[3];
  const float* W_ih    = (const float*)d_in[4];
  const float* W_hh    = (const float*)d_in[5];
  const float* b_ih    = (const float*)d_in[6];
  const float* b_hh    = (const float*)d_in[7];
  const float* Wq      = (const float*)d_in[8];
  const float* bq      = (const float*)d_in[9];
  const float* Wk      = (const float*)d_in[10];
  const float* bk      = (const float*)d_in[11];
  const float* Wv      = (const float*)d_in[12];
  const float* bv      = (const float*)d_in[13];
  const float* W_out   = (const float*)d_in[14];
  const float* b_out   = (const float*)d_in[15];

  char* ws = (char*)d_ws;
  float*  lstm_out = (float*)(ws + OFF_LSTMOUT);
  u64*    hx       = (u64*)(ws + OFF_HX);
  u64*    packed   = (u64*)(ws + OFF_PACKED);
  u64*    packed2  = (u64*)(ws + OFF_PACKED2);
  uint*   hitcnt   = (uint*)(ws + OFF_HITCNT);
  float*  qmargin  = (float*)(ws + OFF_QMARGIN);
  uint*   hitbuf   = (uint*)(ws + OFF_HITBUF);
  float*  xW       = (float*)(ws + OFF_XW);
  float*  qkv      = (float*)(ws + OFF_QKV);
  float*  wiht     = (float*)(ws + OFF_WIHT);
  float*  wqkvt    = (float*)(ws + OFF_WQKVT);
  float*  biasih   = (float*)(ws + OFF_BIASIH);
  float*  bqkv     = (float*)(ws + OFF_BQKV);
  float*  dnscale  = (float*)(ws + OFF_DNSCALE);
  float*  closest  = (float*)(ws + OFF_CLOSEST);
  float*  av       = (float*)(ws + OFF_AV);
  ushort* demb16   = (ushort*)(ws + OFF_DEMB16);
  ushort* a16      = (ushort*)(ws + OFF_A16);

  hipMemsetAsync(d_ws, 0, (size_t)MEMSET_BYTES, stream);

  hipLaunchKernelGGL(prep_kernel, dim3(8817), dim3(256), 0, stream,
                     x, emb, demb, W_ih, Wq, Wk, Wv, b_ih, b_hh, bq, bk, bv,
                     dnscale, demb16, a16, wiht, wqkvt, biasih, bqkv,
                     qmargin, packed2);
  hipLaunchKernelGGL(xw_kernel, dim3(256), dim3(256), 0, stream,
                     x, emb, wiht, biasih, xW);
  hipLaunchKernelGGL(knn_kernel, dim3(256), dim3(256), 0, stream,
                     a16, demb16, dnscale, qmargin, packed, hitcnt, hitbuf);
  hipLaunchKernelGGL(rescore_kernel, dim3(512), dim3(256), 0, stream,
                     hitbuf, hitcnt, packed, x, emb, demb, dnscale, packed2);
  hipLaunchKernelGGL(lstm_kernel, dim3(256), dim3(512), 0, stream,
                     lengths, W_hh, xW, lstm_out, hx);
  hipLaunchKernelGGL(closest_kernel, dim3(64), dim3(128), 0, stream,
                     packed2, demb, closest);
  hipLaunchKernelGGL(qkv_kernel, dim3(256), dim3(256), 0, stream,
                     lstm_out, wqkvt, bqkv, qkv);
  hipLaunchKernelGGL(attn_kernel, dim3(64), dim3(256), 0, stream,
                     qkv, lengths, closest, W_out, b_out, av);
  hipLaunchKernelGGL(final_kernel, dim3(196), dim3(256), 0, stream,
                     emb, av, (float*)d_out);
}

// Round 9
// 616.279 us; speedup vs baseline: 11.6843x; 1.6434x over previous
//
#include <hip/hip_runtime.h>

typedef unsigned int uint;
typedef unsigned short ushort;
typedef unsigned long long u64;

#define NITEMS 50000
#define NDATA  20000
#define BLKCAP 4096u          // per-block hit region (uint entries)
#define OVCAP  65536u         // overflow region

// ---------------- ws layout (bytes) ----------------
#define OFF_LSTMOUT   0x0000000ULL  // [64][64][256] f32 = 4 MB   (memset 0: covers t>=len masking)
#define OFF_HX        0x0400000ULL  // u64[2 parity][64 item][256 j] = 256 KB (memset 0: tag 0)
#define OFF_PACKED    0x0440000ULL  // [4096] u64 = 32 KB         (memset 0: argmax identity, bf16 pass)
#define OFF_PACKED2   0x0448000ULL  // [4096] u64 = 32 KB         (memset 0 + prep seeds zero rows)
#define OFF_HITCNTS   0x0450000ULL  // [512] uint                  (memset 0)
#define OFF_OHITCNT   0x0450800ULL  // uint                        (memset 0)
#define MEMSET_BYTES  0x0451000ULL
#define OFF_QMARGIN   0x0451000ULL  // [4096] f32 (margin, or -1e30 sentinel for zero rows)
#define OFF_XW        0x0560000ULL  // [4096][1024] f32 = 16 MB
#define OFF_QKV       0x1560000ULL  // [4096][768] f32 = 12 MB (cols: 0-255 q, 256-511 k, 512-767 v)
#define OFF_HITBUF    OFF_QKV       // 512*4096 + 65536 uints = 8.25 MB; dead before qkv writes
#define OFF_WIHT      0x2160000ULL  // [128][1024] f32 transposed W_ih
#define OFF_WQKVT     0x21E0000ULL  // [256][768] f32 transposed Wq|Wk|Wv
#define OFF_BIASIH    0x22A0000ULL  // [1024] f32 (b_ih + b_hh)
#define OFF_BQKV      0x22A1000ULL  // [768] f32
#define OFF_DNSCALE   0x22A2000ULL  // [20000] f32  1/max(norm,eps)
#define OFF_CLOSEST   0x22B6000ULL  // [64][128] f32
#define OFF_AV        0x22BE000ULL  // [128][64] f32 (transposed: [e][b])
#define OFF_DEMB16    0x22C6000ULL  // [20000][128] bf16 = 5.12 MB
#define OFF_A16       0x27A8000ULL  // [4096][128] bf16 = 1 MB  (emb[x], pre-posenc)
// end 0x28A8000 = 42.7 MB

__device__ __forceinline__ ushort f2bf(float f) {
  union { float f; uint u; } v; v.f = f;
  uint u = v.u;
  return (ushort)((u + 0x7FFFu + ((u >> 16) & 1u)) >> 16);  // RNE
}
__device__ __forceinline__ uint fkey(float f) {  // monotone float->uint
  union { float f; uint u; } v; v.f = f;
  return (v.u & 0x80000000u) ? ~v.u : (v.u | 0x80000000u);
}
__device__ __forceinline__ u64 shfl_xor_u64(u64 v, int off) {
  uint lo = (uint)v, hi = (uint)(v >> 32);
  lo = (uint)__shfl_xor((int)lo, off);
  hi = (uint)__shfl_xor((int)hi, off);
  return ((u64)hi << 32) | (u64)lo;
}

typedef __attribute__((ext_vector_type(8))) short short8;   // 8 bf16 (4 VGPRs)
typedef __attribute__((ext_vector_type(4))) float floatx4;  // MFMA acc

#define R32(M) M(0) M(1) M(2) M(3) M(4) M(5) M(6) M(7) M(8) M(9) M(10) M(11) \
  M(12) M(13) M(14) M(15) M(16) M(17) M(18) M(19) M(20) M(21) M(22) M(23) \
  M(24) M(25) M(26) M(27) M(28) M(29) M(30) M(31)

// ================= prep: norms / bf16 conversions / transposes / biases / kNN margins =================
__global__ __launch_bounds__(256) void prep_kernel(
    const int* __restrict__ x,
    const float* __restrict__ emb, const float* __restrict__ demb,
    const float* __restrict__ W_ih,
    const float* __restrict__ Wq, const float* __restrict__ Wk, const float* __restrict__ Wv,
    const float* __restrict__ b_ih, const float* __restrict__ b_hh,
    const float* __restrict__ bq, const float* __restrict__ bk, const float* __restrict__ bv,
    float* __restrict__ dnscale, ushort* __restrict__ demb16, ushort* __restrict__ a16,
    float* __restrict__ wiht, float* __restrict__ wqkvt,
    float* __restrict__ biasih, float* __restrict__ bqkv,
    float* __restrict__ qmargin, u64* __restrict__ packed2)
{
  int blk = blockIdx.x, tid = threadIdx.x;
  if (blk < 5000) {                       // 1/max(||demb_row||, eps)
    int row = blk * 4 + (tid >> 6);
    int lane = tid & 63;
    float2 d = *(const float2*)(demb + (size_t)row * 128 + lane * 2);
    float s = d.x * d.x + d.y * d.y;
    for (int off = 32; off; off >>= 1) s += __shfl_xor(s, off);
    if (lane == 0) dnscale[row] = 1.0f / fmaxf(sqrtf(s), 1e-8f);
  } else if (blk < 6250) {                // demb -> bf16
    size_t base = ((size_t)(blk - 5000) * 256 + tid) * 8;
    float4 f1 = *(const float4*)(demb + base);
    float4 f2 = *(const float4*)(demb + base + 4);
    uint4 o;
    o.x = (uint)f2bf(f1.x) | ((uint)f2bf(f1.y) << 16);
    o.y = (uint)f2bf(f1.z) | ((uint)f2bf(f1.w) << 16);
    o.z = (uint)f2bf(f2.x) | ((uint)f2bf(f2.y) << 16);
    o.w = (uint)f2bf(f2.z) | ((uint)f2bf(f2.w) << 16);
    *(uint4*)(demb16 + base) = o;
  } else if (blk < 6506) {                // emb[x] rows -> bf16 (initial_embs, pre-posenc)
    int idx = (blk - 6250) * 256 + tid;   // < 65536
    int m = idx >> 4, seg = idx & 15;
    const float* src = emb + (size_t)x[m] * 128 + seg * 8;
    float4 f1 = *(const float4*)(src);
    float4 f2 = *(const float4*)(src + 4);
    uint4 o;
    o.x = (uint)f2bf(f1.x) | ((uint)f2bf(f1.y) << 16);
    o.y = (uint)f2bf(f1.z) | ((uint)f2bf(f1.w) << 16);
    o.z = (uint)f2bf(f2.x) | ((uint)f2bf(f2.y) << 16);
    o.w = (uint)f2bf(f2.z) | ((uint)f2bf(f2.w) << 16);
    *(uint4*)(a16 + (size_t)m * 128 + seg * 8) = o;
  } else if (blk < 7018) {                // W_ih (1024,128) -> [e][r]
    int f = (blk - 6506) * 256 + tid;
    int r = f >> 7, e = f & 127;
    wiht[e * 1024 + r] = W_ih[f];
  } else if (blk < 7786) {                // Wq/Wk/Wv (256,256) -> [e][w*256+r]
    int f = (blk - 7018) * 256 + tid;
    int w = f >> 16; int rem = f & 65535;
    int r = rem >> 8, e = rem & 255;
    const float* src = (w == 0) ? Wq : (w == 1) ? Wk : Wv;
    wqkvt[e * 768 + w * 256 + r] = src[rem];
  } else if (blk < 7790) {
    int idx = (blk - 7786) * 256 + tid;
    if (idx < 1024) biasih[idx] = b_ih[idx] + b_hh[idx];
  } else if (blk < 7793) {
    int idx = (blk - 7790) * 256 + tid;
    if (idx < 768) {
      int w = idx >> 8; int r = idx & 255;
      const float* src = (w == 0) ? bq : (w == 1) ? bk : bv;
      bqkv[idx] = src[r];
    }
  } else {                                // kNN margin per query row + zero-row seeds
    int row = (blk - 7793) * 4 + (tid >> 6);   // 1024 blocks -> 4096 rows
    int lane = tid & 63;
    float2 d = *(const float2*)(emb + (size_t)x[row] * 128 + lane * 2);
    float s = d.x * d.x + d.y * d.y;
    for (int off = 32; off; off >>= 1) s += __shfl_xor(s, off);
    if (lane == 0) {
      if (s == 0.f) {
        qmargin[row] = -1e30f;            // sentinel: thr = best+1e30 -> no hits ever
        // all sims exactly +0 -> argmax = first index (n=0), exact
        packed2[row] = ((u64)fkey(0.0f) << 32) | 0xFFFFFFFFull;
      } else {
        // PROVABLE bound: |sim_bf16 - sim_exact| <= 2*2^-8*||q|| (q AND d rounding,
        // Cauchy-Schwarz) ~= 0.0157||q||; 0.017||q|| adds fp32-accum slack.
        qmargin[row] = 0.017f * sqrtf(s) + 1e-5f;
      }
    }
  }
}

// ================= xW = (emb[x]+posenc) @ W_ih^T + (b_ih+b_hh) =================
__global__ __launch_bounds__(256) void xw_kernel(
    const int* __restrict__ x, const float* __restrict__ emb,
    const float* __restrict__ wiht, const float* __restrict__ biasih,
    float* __restrict__ xW)
{
  __shared__ __align__(16) float At[128 * 16];   // [e][m]
  int blk = blockIdx.x, tid = threadIdx.x;
  int m0 = blk * 16;
  for (int c = 0; c < 8; ++c) {
    int idx = c * 256 + tid;
    int mm = idx >> 7, e = idx & 127;
    int m = m0 + mm;
    int bcol = m & 63;                 // PositionalEncoding indexed by BATCH (faithful quirk)
    int xv = x[m];
    float val = emb[(size_t)xv * 128 + e];
    int j = e >> 1;
    float arg = (float)bcol * __expf((float)j * -0.14391157f);  // exp(-j*ln(10000)/64)
    val += (e & 1) ? cosf(arg) : sinf(arg);
    At[e * 16 + mm] = val;
  }
  __syncthreads();
  int quad = tid >> 6, l = tid & 63;
  for (int rp = 0; rp < 4; ++rp) {
    int r = rp * 256 + l * 4;
    float acc[4][4] = {};
    for (int e = 0; e < 128; ++e) {
      float4 wv4 = *(const float4*)(wiht + e * 1024 + r);
      float4 av4 = *(const float4*)(At + e * 16 + quad * 4);
      float am[4] = {av4.x, av4.y, av4.z, av4.w};
      float wr4[4] = {wv4.x, wv4.y, wv4.z, wv4.w};
      #pragma unroll
      for (int mi = 0; mi < 4; ++mi)
        #pragma unroll
        for (int ri = 0; ri < 4; ++ri)
          acc[mi][ri] += am[mi] * wr4[ri];
    }
    float4 bv4 = *(const float4*)(biasih + r);
    #pragma unroll
    for (int mi = 0; mi < 4; ++mi) {
      size_t m = (size_t)(m0 + quad * 4 + mi);
      float4 o;
      o.x = acc[mi][0] + bv4.x; o.y = acc[mi][1] + bv4.y;
      o.z = acc[mi][2] + bv4.z; o.w = acc[mi][3] + bv4.w;
      *(float4*)(xW + m * 1024 + r) = o;
    }
  }
}

// ================= kNN: grid 512 = 32 m-tiles(128) x 16 chunks(1250). Two MFMA sweeps.
// Sweep A: pure argmax -> chunk-final per-row best (butterfly). Sweep B: record
// sim >= chunk_best - margin into PER-BLOCK region (LDS counter, no global atomics;
// rare overflow spills to a global overflow region). Superset proof unchanged. =================
__global__ __launch_bounds__(256) void knn_kernel(
    const ushort* __restrict__ a16, const ushort* __restrict__ demb16,
    const float* __restrict__ dnscale, const float* __restrict__ qmargin,
    u64* __restrict__ packed, uint* __restrict__ hitcnts, uint* __restrict__ ohitcnt,
    uint* __restrict__ hitbuf)
{
  __shared__ __align__(16) ushort b_sh[2][64 * 144];
  __shared__ uint lcnt;
  int blk = blockIdx.x, tid = threadIdx.x;
  int chunk = blk & 15, mt = blk >> 4;     // 16 chunks x 32 m-tiles
  int wv = tid >> 6, lane = tid & 63;
  int col = lane & 15, quad = lane >> 4;
  int M0 = mt * 128;
  if (tid == 0) lcnt = 0;
  short8 afrag[2][4];
  #pragma unroll
  for (int s = 0; s < 2; ++s) {
    int mrow = M0 + s * 64 + wv * 16 + col;
    #pragma unroll
    for (int kf = 0; kf < 4; ++kf)
      afrag[s][kf] = *(const short8*)(a16 + (size_t)mrow * 128 + kf * 32 + quad * 8);
  }
  float best[2][4] = {{-1e30f,-1e30f,-1e30f,-1e30f},{-1e30f,-1e30f,-1e30f,-1e30f}};
  int bidx[2][4] = {};
  int nbase = chunk * 1250, nend = nbase + 1250;
  const int niter = 20;                    // ceil(1250/64)
  int srow = tid >> 4, sseg = tid & 15;
  uint4 stg[4]; float scr[4];

  // ================== SWEEP A: pure argmax ==================
  #pragma unroll
  for (int p = 0; p < 4; ++p) {
    int n = nbase + p * 16 + srow;
    uint4 v = {0u,0u,0u,0u};
    if (n < nend) v = *(const uint4*)(demb16 + (size_t)n * 128 + sseg * 8);
    stg[p] = v;
  }
  #pragma unroll
  for (int ns = 0; ns < 4; ++ns) {
    int n = nbase + ns * 16 + col;
    scr[ns] = (n < nend) ? dnscale[n] : 0.f;
  }
  for (int it = 0; it < niter; ++it) {
    int n0 = nbase + it * 64;
    ushort* bsh = b_sh[it & 1];
    #pragma unroll
    for (int p = 0; p < 4; ++p)
      *(uint4*)(&bsh[(p * 16 + srow) * 144 + sseg * 8]) = stg[p];
    float mysc[4] = {scr[0], scr[1], scr[2], scr[3]};
    __syncthreads();
    if (it + 1 < niter) {                  // prefetch next tile while computing this one
      int nb = n0 + 64;
      #pragma unroll
      for (int p = 0; p < 4; ++p) {
        int n = nb + p * 16 + srow;
        uint4 v = {0u,0u,0u,0u};
        if (n < nend) v = *(const uint4*)(demb16 + (size_t)n * 128 + sseg * 8);
        stg[p] = v;
      }
      #pragma unroll
      for (int ns = 0; ns < 4; ++ns) {
        int n = nb + ns * 16 + col;
        scr[ns] = (n < nend) ? dnscale[n] : 0.f;
      }
    }
    #pragma unroll
    for (int ns = 0; ns < 4; ++ns) {
      short8 bfr[4];
      #pragma unroll
      for (int kf = 0; kf < 4; ++kf)
        bfr[kf] = *(const short8*)(&bsh[(ns * 16 + col) * 144 + kf * 32 + quad * 8]);
      int n = n0 + ns * 16 + col;
      float sc = mysc[ns];
      bool valid = (n < nend);
      #pragma unroll
      for (int s = 0; s < 2; ++s) {
        floatx4 acc = {0.f, 0.f, 0.f, 0.f};
        #pragma unroll
        for (int kf = 0; kf < 4; ++kf)
          acc = __builtin_amdgcn_mfma_f32_16x16x32_bf16(afrag[s][kf], bfr[kf], acc, 0, 0, 0);
        #pragma unroll
        for (int r = 0; r < 4; ++r) {        // D[row=quad*4+r][col=lane&15]
          float sim = acc[r] * sc;
          if (valid && sim > best[s][r]) { best[s][r] = sim; bidx[s][r] = n; }
        }
      }
    }
  }
  // chunk-final per-row best (butterfly over the 16 col lanes) + global argmax output
  float thr[2][4];
  #pragma unroll
  for (int s = 0; s < 2; ++s)
    #pragma unroll
    for (int r = 0; r < 4; ++r) {
      u64 p = ((u64)fkey(best[s][r]) << 32) | (u64)(0xFFFFFFFFu - (uint)bidx[s][r]);
      #pragma unroll
      for (int off = 1; off < 16; off <<= 1) {   // col bits only: stays in row group
        u64 o = shfl_xor_u64(p, off);
        if (o > p) p = o;
      }
      int m = M0 + s * 64 + wv * 16 + quad * 4 + r;
      union { uint u; float f; } bu;
      uint k = (uint)(p >> 32);
      bu.u = (k & 0x80000000u) ? (k & 0x7FFFFFFFu) : ~k;   // unfkey
      thr[s][r] = bu.f - qmargin[m];
      if (col == 0)
        atomicMax((unsigned long long*)&packed[m], (unsigned long long)p);
    }
  __syncthreads();

  // ================== SWEEP B: record candidates >= thr (per-block region) ==================
  uint* myregion = hitbuf + (size_t)blk * BLKCAP;
  uint* ovregion = hitbuf + (size_t)512 * BLKCAP;
  #pragma unroll
  for (int p = 0; p < 4; ++p) {
    int n = nbase + p * 16 + srow;
    uint4 v = {0u,0u,0u,0u};
    if (n < nend) v = *(const uint4*)(demb16 + (size_t)n * 128 + sseg * 8);
    stg[p] = v;
  }
  #pragma unroll
  for (int ns = 0; ns < 4; ++ns) {
    int n = nbase + ns * 16 + col;
    scr[ns] = (n < nend) ? dnscale[n] : 0.f;
  }
  for (int it = 0; it < niter; ++it) {
    int n0 = nbase + it * 64;
    ushort* bsh = b_sh[it & 1];
    #pragma unroll
    for (int p = 0; p < 4; ++p)
      *(uint4*)(&bsh[(p * 16 + srow) * 144 + sseg * 8]) = stg[p];
    float mysc[4] = {scr[0], scr[1], scr[2], scr[3]};
    __syncthreads();
    if (it + 1 < niter) {
      int nb = n0 + 64;
      #pragma unroll
      for (int p = 0; p < 4; ++p) {
        int n = nb + p * 16 + srow;
        uint4 v = {0u,0u,0u,0u};
        if (n < nend) v = *(const uint4*)(demb16 + (size_t)n * 128 + sseg * 8);
        stg[p] = v;
      }
      #pragma unroll
      for (int ns = 0; ns < 4; ++ns) {
        int n = nb + ns * 16 + col;
        scr[ns] = (n < nend) ? dnscale[n] : 0.f;
      }
    }
    #pragma unroll
    for (int ns = 0; ns < 4; ++ns) {
      short8 bfr[4];
      #pragma unroll
      for (int kf = 0; kf < 4; ++kf)
        bfr[kf] = *(const short8*)(&bsh[(ns * 16 + col) * 144 + kf * 32 + quad * 8]);
      int n = n0 + ns * 16 + col;
      float sc = mysc[ns];
      bool valid = (n < nend);
      #pragma unroll
      for (int s = 0; s < 2; ++s) {
        floatx4 acc = {0.f, 0.f, 0.f, 0.f};
        #pragma unroll
        for (int kf = 0; kf < 4; ++kf)
          acc = __builtin_amdgcn_mfma_f32_16x16x32_bf16(afrag[s][kf], bfr[kf], acc, 0, 0, 0);
        #pragma unroll
        for (int r = 0; r < 4; ++r) {
          float sim = acc[r] * sc;
          bool hit = valid && (sim >= thr[s][r]);   // ~2e-3 probability
          u64 mask = __ballot(hit);
          if (mask) {
            uint lcntv = (uint)__popcll(mask);
            int leader = __ffsll((unsigned long long)mask) - 1;
            uint base = 0;
            if (lane == leader) base = atomicAdd(&lcnt, lcntv);   // LDS atomic: fast
            base = (uint)__shfl((int)base, leader);
            if (hit) {
              uint pos = base + (uint)__popcll(mask & ((1ull << lane) - 1ull));
              uint mm = (uint)(M0 + s * 64 + wv * 16 + quad * 4 + r);
              uint rec = (mm << 15) | (uint)n;
              if (pos < BLKCAP) {
                myregion[pos] = rec;
              } else {                               // rare spill
                uint op = atomicAdd(ohitcnt, 1u);
                if (op < OVCAP) ovregion[op] = rec;
              }
            }
          }
        }
      }
    }
  }
  __syncthreads();
  if (tid == 0) hitcnts[blk] = lcnt;
}

// ================= rescore: exact-dot every recorded candidate (region-per-block,
// + overflow region, + gid<4096 bf16-winner fallback -> packed2 always valid) =================
__global__ __launch_bounds__(256) void rescore_kernel(
    const uint* __restrict__ hitbuf, const uint* __restrict__ hitcnts,
    const uint* __restrict__ ohitcnt, const u64* __restrict__ packed,
    const int* __restrict__ x, const float* __restrict__ emb,
    const float* __restrict__ demb, const float* __restrict__ dnscale,
    u64* __restrict__ packed2)
{
  int blk = blockIdx.x, tid = threadIdx.x;
  uint gid = blk * 256 + tid;
  if (gid < 4096) {                            // guaranteed fallback: bf16 winner exact
    uint m = gid;
    uint n = 0xFFFFFFFFu - (uint)(packed[m] & 0xFFFFFFFFull);
    if (n < NDATA) {
      const float* q = emb + (size_t)x[m] * 128;
      const float* d = demb + (size_t)n * 128;
      double p = 0.0;
      #pragma unroll 8
      for (int e = 0; e < 128; e += 2) {
        float2 qv = *(const float2*)(q + e);
        float2 dv = *(const float2*)(d + e);
        p += (double)qv.x * (double)dv.x + (double)qv.y * (double)dv.y;
      }
      float sx = (float)(p * (double)dnscale[n]);
      u64 key = ((u64)fkey(sx) << 32) | (u64)(0xFFFFFFFFu - n);
      atomicMax((unsigned long long*)&packed2[m], (unsigned long long)key);
    }
  }
  const uint* src; uint cnt; uint stride;
  if (blk < 512) {                             // per-block region
    src = hitbuf + (size_t)blk * BLKCAP;
    cnt = hitcnts[blk]; if (cnt > BLKCAP) cnt = BLKCAP;
    stride = 256;
  } else {                                     // overflow region (blocks 512..527)
    src = hitbuf + (size_t)512 * BLKCAP + (blk - 512) * 256 + 0;
    // handled via flat index below instead:
    src = hitbuf + (size_t)512 * BLKCAP;
    cnt = *ohitcnt; if (cnt > OVCAP) cnt = OVCAP;
    stride = 16 * 256;
  }
  uint start = (blk < 512) ? tid : (uint)((blk - 512) * 256 + tid);
  for (uint h = start; h < cnt; h += stride) {
    uint rec = src[h];
    uint m = rec >> 15, n = rec & 0x7FFFu;
    if (m >= 4096 || n >= NDATA) continue;
    const float* q = emb + (size_t)x[m] * 128;
    const float* d = demb + (size_t)n * 128;
    double p = 0.0;
    #pragma unroll 8
    for (int e = 0; e < 128; e += 2) {
      float2 qv = *(const float2*)(q + e);
      float2 dv = *(const float2*)(d + e);
      p += (double)qv.x * (double)dv.x + (double)qv.y * (double)dv.y;
    }
    float sx = (float)(p * (double)dnscale[n]);
    u64 key = ((u64)fkey(sx) << 32) | (u64)(0xFFFFFFFFu - n);
    atomicMax((unsigned long long*)&packed2[m], (unsigned long long)key);
  }
}

// ================= LSTM: 4 blocks/item, asm-pinned reg-resident W_hh, fence-free
// relaxed-atomic h exchange ({f32,u32 tag} packed, parity double-buffer) =================
__global__ __launch_bounds__(512, 2) void lstm_kernel(
    const int* __restrict__ lengths, const float* __restrict__ Whh,
    const float* __restrict__ xW, float* __restrict__ lstm_out,
    u64* __restrict__ hx)
{
  __shared__ __align__(16) float h_sh[256];
  __shared__ float part_sh[512];
  int blk = blockIdx.x, tid = threadIdx.x;
  int b = blk & 63, q = blk >> 6;          // item b blocks {b,64+b,128+b,192+b}
  int row_local = tid >> 1, half = tid & 1;
  int gate = row_local >> 6, jloc = row_local & 63;
  int grow = gate * 256 + q * 64 + jloc;
  const float4* wp4 = (const float4*)(Whh + (size_t)grow * 256 + half * 128);
#define WDECL(i) float4 tt##i = wp4[i]; \
  float w##i##x = tt##i.x, w##i##y = tt##i.y, w##i##z = tt##i.z, w##i##w = tt##i.w;
  R32(WDECL)
  // pin: asm-produced values cannot be rematerialized -> loads can't sink into the loop
#define WPIN(i) asm volatile("" : "+v"(w##i##x), "+v"(w##i##y), "+v"(w##i##z), "+v"(w##i##w));
  R32(WPIN)
  int len = lengths[b];
  if (tid < 256) h_sh[tid] = 0.f;
  float cval = 0.f;
  int jr = (tid < q * 64) ? tid : tid + 64;  // remote-j map for tid<192 (skips own quarter)
  __syncthreads();
  for (int t = 0; t < len; ++t) {
    if (t > 0) {
      if (tid < 192) {                     // fetch partners' h_t (tag t, parity t&1)
        u64* slot = hx + (((size_t)(t & 1) * 64 + b) * 256 + jr);
        u64 v = 0; int guard = 0;
        while (true) {
          v = __hip_atomic_load(slot, __ATOMIC_RELAXED, __HIP_MEMORY_SCOPE_AGENT);
          if ((uint)v == (uint)t || ++guard > (1 << 22)) break;
          __builtin_amdgcn_s_sleep(1);
        }
        union { uint u; float f; } cv; cv.u = (uint)(v >> 32);
        h_sh[jr] = cv.f;
      }
      __syncthreads();
    }
    const float4* h4 = (const float4*)(h_sh + half * 128);
    float acc = 0.f;
#define WACC(i) { float4 hv = h4[i]; \
    acc += w##i##x * hv.x + w##i##y * hv.y + w##i##z * hv.z + w##i##w * hv.w; }
    R32(WACC)
    part_sh[tid] = acc;
    __syncthreads();
    if (tid < 64) {
      const float* xwrow = xW + ((size_t)t * 64 + b) * 1024 + q * 64 + tid;
      float gi = part_sh[tid * 2]         + part_sh[tid * 2 + 1]         + xwrow[0];
      float gf = part_sh[(64 + tid) * 2]  + part_sh[(64 + tid) * 2 + 1]  + xwrow[256];
      float gg = part_sh[(128 + tid) * 2] + part_sh[(128 + tid) * 2 + 1] + xwrow[512];
      float go = part_sh[(192 + tid) * 2] + part_sh[(192 + tid) * 2 + 1] + xwrow[768];
      float ii = 1.f / (1.f + __expf(-gi));
      float ff = 1.f / (1.f + __expf(-gf));
      float oo = 1.f / (1.f + __expf(-go));
      cval = ff * cval + ii * tanhf(gg);
      float hv = oo * tanhf(cval);
      int j = q * 64 + tid;
      lstm_out[((size_t)b * 64 + t) * 256 + j] = hv;
      h_sh[j] = hv;                        // own quarter stays local
      union { float f; uint u; } cu; cu.f = hv;
      u64 pk = ((u64)cu.u << 32) | (u64)(uint)(t + 1);
      __hip_atomic_store(hx + (((size_t)((t + 1) & 1) * 64 + b) * 256 + j), pk,
                         __ATOMIC_RELAXED, __HIP_MEMORY_SCOPE_AGENT);
    }
    __syncthreads();                       // h_sh own-writes ordered before next-iter reads
  }
}

// ================= closest = mean_t data_emb[idx] =================
__global__ __launch_bounds__(128) void closest_kernel(
    const u64* __restrict__ packed2, const float* __restrict__ demb,
    float* __restrict__ closest)
{
  int b = blockIdx.x, tid = threadIdx.x;
  float s = 0.f;
  for (int t = 0; t < 64; ++t) {
    uint low = (uint)(packed2[t * 64 + b] & 0xFFFFFFFFull);
    uint n = 0xFFFFFFFFu - low;
    if (n >= NDATA) n = 0;                 // safety clamp: never page-fault
    s += demb[(size_t)n * 128 + tid];
  }
  closest[b * 128 + tid] = s * (1.0f / 64.0f);
}

// ================= q/k/v = lstm_out @ W{q,k,v}^T + bias =================
__global__ __launch_bounds__(256) void qkv_kernel(
    const float* __restrict__ lstm_out, const float* __restrict__ wqkvt,
    const float* __restrict__ bqkv, float* __restrict__ qkv)
{
  __shared__ __align__(16) float At[256 * 16];   // [e][m]
  int blk = blockIdx.x, tid = threadIdx.x;
  int m0 = blk * 16;
  for (int c = 0; c < 16; ++c)
    At[tid * 16 + c] = lstm_out[((size_t)m0 + c) * 256 + tid];
  __syncthreads();
  int quad = tid >> 6, l = tid & 63;
  for (int rp = 0; rp < 3; ++rp) {
    int r = rp * 256 + l * 4;
    float acc[4][4] = {};
    for (int e = 0; e < 256; ++e) {
      float4 wv4 = *(const float4*)(wqkvt + (size_t)e * 768 + r);
      float4 av4 = *(const float4*)(At + e * 16 + quad * 4);
      float am[4] = {av4.x, av4.y, av4.z, av4.w};
      float wr4[4] = {wv4.x, wv4.y, wv4.z, wv4.w};
      #pragma unroll
      for (int mi = 0; mi < 4; ++mi)
        #pragma unroll
        for (int ri = 0; ri < 4; ++ri)
          acc[mi][ri] += am[mi] * wr4[ri];
    }
    float4 bv4 = *(const float4*)(bqkv + r);
    #pragma unroll
    for (int mi = 0; mi < 4; ++mi) {
      size_t m = (size_t)(m0 + quad * 4 + mi);
      float4 o;
      o.x = acc[mi][0] + bv4.x; o.y = acc[mi][1] + bv4.y;
      o.z = acc[mi][2] + bv4.z; o.w = acc[mi][3] + bv4.w;
      *(float4*)(qkv + m * 768 + r) = o;
    }
  }
}

// ================= attention: softmax col-sums, weighted V, W_out proj, *closest =================
__global__ __launch_bounds__(256) void attn_kernel(
    const float* __restrict__ qkv, const int* __restrict__ lengths,
    const float* __restrict__ closest, const float* __restrict__ W_out,
    const float* __restrict__ b_out, float* __restrict__ av)
{
  __shared__ float k_sh[64 * 257];               // stride 257 -> conflict-free row reads
  __shared__ __align__(16) float q_sh[4 * 256];
  __shared__ float wpart[4 * 64];
  __shared__ float wtot[64];
  __shared__ float out_sh[256];
  int b = blockIdx.x, tid = threadIdx.x;
  int wv = tid >> 6, lane = tid & 63;
  int len = lengths[b];
  for (int s = 0; s < 64; ++s)
    k_sh[s * 257 + tid] = qkv[((size_t)b * 64 + s) * 768 + 256 + tid];
  wpart[tid] = 0.f;
  for (int tq = 0; tq < 16; ++tq) {
    __syncthreads();
    #pragma unroll
    for (int c = 0; c < 4; ++c)
      q_sh[c * 256 + tid] = qkv[((size_t)b * 64 + tq * 4 + c) * 768 + tid];
    __syncthreads();
    const float* krow = k_sh + lane * 257;
    const float* qrow = q_sh + wv * 256;
    float sc = 0.f;
    #pragma unroll 8
    for (int h = 0; h < 256; ++h)
      sc += qrow[h] * krow[h];
    sc *= 0.0625f;                         // 1/sqrt(256)
    bool vs = (lane < len);                // key-position mask
    float scm = vs ? sc : -1e30f;
    float mx = scm;
    for (int off = 32; off; off >>= 1) mx = fmaxf(mx, __shfl_xor(mx, off));
    float e = vs ? __expf(sc - mx) : 0.f;
    float sum = e;
    for (int off = 32; off; off >>= 1) sum += __shfl_xor(sum, off);
    wpart[wv * 64 + lane] += e / sum;
  }
  __syncthreads();
  if (tid < 64)
    wtot[tid] = (wpart[tid] + wpart[64 + tid] + wpart[128 + tid] + wpart[192 + tid]) * (1.0f / 64.0f);
  __syncthreads();
  {
    float acc = 0.f;
    for (int s = 0; s < 64; ++s)
      acc += wtot[s] * qkv[((size_t)b * 64 + s) * 768 + 512 + tid];
    out_sh[tid] = acc;
  }
  __syncthreads();
  if (tid < 128) {
    const float4* wr = (const float4*)(W_out + (size_t)tid * 256);
    float p = b_out[tid];
    #pragma unroll
    for (int c = 0; c < 64; ++c) {
      float4 u = wr[c];
      p += out_sh[c * 4 + 0] * u.x + out_sh[c * 4 + 1] * u.y
         + out_sh[c * 4 + 2] * u.z + out_sh[c * 4 + 3] * u.w;
    }
    av[tid * 64 + b] = p * closest[b * 128 + tid];   // [e][b] for wave-uniform loads later
  }
}

// ================= out[b][i] = av[:,b] . emb_table[i] =================
__global__ __launch_bounds__(256) void final_kernel(
    const float* __restrict__ emb, const float* __restrict__ av,
    float* __restrict__ out)
{
  int i = blockIdx.x * 256 + threadIdx.x;
  if (i >= NITEMS) return;
  const float4* row = (const float4*)(emb + (size_t)i * 128);
  float acc[64];
  #pragma unroll
  for (int bb = 0; bb < 64; ++bb) acc[bb] = 0.f;
  for (int e4 = 0; e4 < 32; ++e4) {
    float4 u = row[e4];
    float wvv[4] = {u.x, u.y, u.z, u.w};
    const float* ab = av + e4 * 4 * 64;    // wave-uniform addresses -> scalar pipe
    #pragma unroll
    for (int j = 0; j < 4; ++j) {
      #pragma unroll
      for (int bb = 0; bb < 64; ++bb)
        acc[bb] += wvv[j] * ab[j * 64 + bb];
    }
  }
  #pragma unroll
  for (int bb = 0; bb < 64; ++bb)
    out[(size_t)bb * NITEMS + i] = acc[bb];
}

// ================= launch =================
extern "C" void kernel_launch(void* const* d_in, const int* in_sizes, int n_in,
                              void* d_out, int out_size, void* d_ws, size_t ws_size,
                              hipStream_t stream)
{
  const int*   x       = (const int*)d_in[0];
  const int*   lengths = (const int*)d_in[1];
  const float* emb     = (const float*)d_in[2];
  const float* demb    = (const float*)d_in[3];
  const float* W_ih    = (const float*)d_in[4];
  const float* W_hh    = (const float*)d_in[5];
  const float* b_ih    = (const float*)d_in[6];
  const float* b_hh    = (const float*)d_in[7];
  const float* Wq      = (const float*)d_in[8];
  const float* bq      = (const float*)d_in[9];
  const float* Wk      = (const float*)d_in[10];
  const float* bk      = (const float*)d_in[11];
  const float* Wv      = (const float*)d_in[12];
  const float* bv      = (const float*)d_in[13];
  const float* W_out   = (const float*)d_in[14];
  const float* b_out   = (const float*)d_in[15];

  char* ws = (char*)d_ws;
  float*  lstm_out = (float*)(ws + OFF_LSTMOUT);
  u64*    hx       = (u64*)(ws + OFF_HX);
  u64*    packed   = (u64*)(ws + OFF_PACKED);
  u64*    packed2  = (u64*)(ws + OFF_PACKED2);
  uint*   hitcnts  = (uint*)(ws + OFF_HITCNTS);
  uint*   ohitcnt  = (uint*)(ws + OFF_OHITCNT);
  float*  qmargin  = (float*)(ws + OFF_QMARGIN);
  uint*   hitbuf   = (uint*)(ws + OFF_HITBUF);
  float*  xW       = (float*)(ws + OFF_XW);
  float*  qkv      = (float*)(ws + OFF_QKV);
  float*  wiht     = (float*)(ws + OFF_WIHT);
  float*  wqkvt    = (float*)(ws + OFF_WQKVT);
  float*  biasih   = (float*)(ws + OFF_BIASIH);
  float*  bqkv     = (float*)(ws + OFF_BQKV);
  float*  dnscale  = (float*)(ws + OFF_DNSCALE);
  float*  closest  = (float*)(ws + OFF_CLOSEST);
  float*  av       = (float*)(ws + OFF_AV);
  ushort* demb16   = (ushort*)(ws + OFF_DEMB16);
  ushort* a16      = (ushort*)(ws + OFF_A16);

  hipMemsetAsync(d_ws, 0, (size_t)MEMSET_BYTES, stream);

  hipLaunchKernelGGL(prep_kernel, dim3(8817), dim3(256), 0, stream,
                     x, emb, demb, W_ih, Wq, Wk, Wv, b_ih, b_hh, bq, bk, bv,
                     dnscale, demb16, a16, wiht, wqkvt, biasih, bqkv,
                     qmargin, packed2);
  hipLaunchKernelGGL(xw_kernel, dim3(256), dim3(256), 0, stream,
                     x, emb, wiht, biasih, xW);
  hipLaunchKernelGGL(knn_kernel, dim3(512), dim3(256), 0, stream,
                     a16, demb16, dnscale, qmargin, packed, hitcnts, ohitcnt, hitbuf);
  hipLaunchKernelGGL(rescore_kernel, dim3(528), dim3(256), 0, stream,
                     hitbuf, hitcnts, ohitcnt, packed, x, emb, demb, dnscale, packed2);
  hipLaunchKernelGGL(lstm_kernel, dim3(256), dim3(512), 0, stream,
                     lengths, W_hh, xW, lstm_out, hx);
  hipLaunchKernelGGL(closest_kernel, dim3(64), dim3(128), 0, stream,
                     packed2, demb, closest);
  hipLaunchKernelGGL(qkv_kernel, dim3(256), dim3(256), 0, stream,
                     lstm_out, wqkvt, bqkv, qkv);
  hipLaunchKernelGGL(attn_kernel, dim3(64), dim3(256), 0, stream,
                     qkv, lengths, closest, W_out, b_out, av);
  hipLaunchKernelGGL(final_kernel, dim3(196), dim3(256), 0, stream,
                     emb, av, (float*)d_out);
}